// Round 1
// baseline (1578.431 us; speedup 1.0000x reference)
//
#include <hip/hip_runtime.h>
#include <hip/hip_bf16.h>
#include <stdint.h>

// GNN: h=emb[x]; 2x SAGEConv(mean) + ReLU; global_mean_pool by sorted batch; linear -> [G,2]

#define NPB 4  // nodes (waves) per block in conv/pool kernels

__global__ void k_embed(const int* __restrict__ x, const float* __restrict__ emb,
                        float* __restrict__ h, int n_nodes) {
  int gid = blockIdx.x * blockDim.x + threadIdx.x;
  if (gid >= n_nodes * 64) return;
  int node = gid >> 6, f = gid & 63;
  h[gid] = emb[(size_t)x[node] * 64 + f];
}

__global__ void k_hist(const int* __restrict__ dst, int* __restrict__ cnt, int n_edges) {
  int e = blockIdx.x * blockDim.x + threadIdx.x;
  if (e < n_edges) atomicAdd(&cnt[dst[e]], 1);
}

// ---- exclusive scan of cnt[n] -> offs[n] (+ offs[n]=n_edges), 1024 items/block ----
__global__ void k_scan1(const int* __restrict__ cnt, int* __restrict__ offs,
                        int* __restrict__ bsums, int n) {
  __shared__ int sdata[256];
  int t = threadIdx.x;
  int base = blockIdx.x * 1024 + t * 4;
  int v[4]; int tot = 0;
#pragma unroll
  for (int k = 0; k < 4; ++k) { int i = base + k; v[k] = (i < n) ? cnt[i] : 0; tot += v[k]; }
  sdata[t] = tot;
  __syncthreads();
  for (int off = 1; off < 256; off <<= 1) {
    int add = (t >= off) ? sdata[t - off] : 0;
    __syncthreads();
    sdata[t] += add;
    __syncthreads();
  }
  int run = (t == 0) ? 0 : sdata[t - 1];
  if (t == 255) bsums[blockIdx.x] = sdata[255];
#pragma unroll
  for (int k = 0; k < 4; ++k) { int i = base + k; if (i < n) offs[i] = run; run += v[k]; }
}

__global__ void k_scan2(int* __restrict__ bsums, int nb) {
  __shared__ int s[256];
  int t = threadIdx.x;
  s[t] = (t < nb) ? bsums[t] : 0;
  __syncthreads();
  for (int off = 1; off < 256; off <<= 1) {
    int add = (t >= off) ? s[t - off] : 0;
    __syncthreads();
    s[t] += add;
    __syncthreads();
  }
  if (t < nb) bsums[t] = (t == 0) ? 0 : s[t - 1];
}

__global__ void k_scan3(int* __restrict__ offs, const int* __restrict__ bsums,
                        int n, int n_edges) {
  int i = blockIdx.x * blockDim.x + threadIdx.x;
  if (i == 0) offs[n] = n_edges;
  if (i < n) offs[i] += bsums[i >> 10];
}

__global__ void k_fill(const int* __restrict__ src, const int* __restrict__ dst,
                       int* __restrict__ cursor, int* __restrict__ csr, int n_edges) {
  int e = blockIdx.x * blockDim.x + threadIdx.x;
  if (e >= n_edges) return;
  int pos = atomicAdd(&cursor[dst[e]], 1);
  csr[pos] = src[e];
}

__global__ void k_transpose4(const float* __restrict__ a0, const float* __restrict__ a1,
                             const float* __restrict__ a2, const float* __restrict__ a3,
                             float* __restrict__ wt) {
  const float* s = (blockIdx.x == 0) ? a0 : (blockIdx.x == 1) ? a1 : (blockIdx.x == 2) ? a2 : a3;
  float* d = wt + blockIdx.x * 4096;
  for (int i = threadIdx.x; i < 4096; i += blockDim.x) {
    int r = i >> 6, c = i & 63;
    d[c * 64 + r] = s[i];
  }
}

// one wave per node; lane = feature. mean-aggregate then out = relu(mean@WlT + self@WrT + b)
__global__ void k_sage(const float* __restrict__ hin, float* __restrict__ hout,
                       const int* __restrict__ offs, const int* __restrict__ csr,
                       const float* __restrict__ wlT, const float* __restrict__ wrT,
                       const float* __restrict__ bias, int n_nodes) {
  __shared__ float sm[NPB][64];
  __shared__ float ss[NPB][64];
  int wid = threadIdx.x >> 6, lane = threadIdx.x & 63;
  int node = blockIdx.x * NPB + wid;
  bool active = node < n_nodes;
  if (active) {
    int beg = offs[node], end = offs[node + 1];
    float a0 = 0.f, a1 = 0.f, a2 = 0.f, a3 = 0.f;
    int j = beg;
    for (; j + 3 < end; j += 4) {
      int s0 = csr[j], s1 = csr[j + 1], s2 = csr[j + 2], s3 = csr[j + 3];
      a0 += hin[(size_t)s0 * 64 + lane];
      a1 += hin[(size_t)s1 * 64 + lane];
      a2 += hin[(size_t)s2 * 64 + lane];
      a3 += hin[(size_t)s3 * 64 + lane];
    }
    for (; j < end; ++j) a0 += hin[(size_t)csr[j] * 64 + lane];
    float sum = (a0 + a1) + (a2 + a3);
    int deg = end - beg;
    sm[wid][lane] = (deg > 0) ? sum / (float)deg : 0.f;
    ss[wid][lane] = hin[(size_t)node * 64 + lane];
  }
  __syncthreads();
  if (active) {
    float out = bias[lane];
    const float* m = sm[wid];
    const float* s = ss[wid];
#pragma unroll 8
    for (int f = 0; f < 64; ++f) {
      out = fmaf(m[f], wlT[f * 64 + lane], out);
      out = fmaf(s[f], wrT[f * 64 + lane], out);
    }
    hout[(size_t)node * 64 + lane] = fmaxf(out, 0.f);
  }
}

// graph segment offsets from sorted batch ids
__global__ void k_goffs(const int* __restrict__ batch, int* __restrict__ goffs,
                        int n_nodes, int n_graphs) {
  int i = blockIdx.x * blockDim.x + threadIdx.x;
  if (i >= n_nodes) return;
  int b = batch[i];
  int bp = (i == 0) ? -1 : batch[i - 1];
  for (int g = bp + 1; g <= b; ++g) goffs[g] = i;
  if (i == n_nodes - 1)
    for (int g = b + 1; g <= n_graphs; ++g) goffs[g] = n_nodes;
}

// one wave per graph: mean-pool then 64->2 matvec via shuffle reduce
__global__ void k_poolout(const float* __restrict__ h, const int* __restrict__ goffs,
                          const float* __restrict__ wout, const float* __restrict__ bout,
                          float* __restrict__ out, int n_graphs) {
  int wid = threadIdx.x >> 6, lane = threadIdx.x & 63;
  int g = blockIdx.x * NPB + wid;
  if (g >= n_graphs) return;
  int beg = goffs[g], end = goffs[g + 1];
  float a0 = 0.f, a1 = 0.f, a2 = 0.f, a3 = 0.f;
  int n = beg;
  for (; n + 3 < end; n += 4) {
    a0 += h[(size_t)n * 64 + lane];
    a1 += h[(size_t)(n + 1) * 64 + lane];
    a2 += h[(size_t)(n + 2) * 64 + lane];
    a3 += h[(size_t)(n + 3) * 64 + lane];
  }
  for (; n < end; ++n) a0 += h[(size_t)n * 64 + lane];
  float sum = (a0 + a1) + (a2 + a3);
  int cnt = end - beg;
  float mean = (cnt > 0) ? sum / (float)cnt : 0.f;
  float p0 = mean * wout[lane];
  float p1 = mean * wout[64 + lane];
  for (int o = 32; o > 0; o >>= 1) {
    p0 += __shfl_down(p0, o);
    p1 += __shfl_down(p1, o);
  }
  if (lane == 0) {
    out[g * 2 + 0] = p0 + bout[0];
    out[g * 2 + 1] = p1 + bout[1];
  }
}

extern "C" void kernel_launch(void* const* d_in, const int* in_sizes, int n_in,
                              void* d_out, int out_size, void* d_ws, size_t ws_size,
                              hipStream_t stream) {
  const int* x = (const int*)d_in[0];
  const int* ei = (const int*)d_in[1];
  const int* batch = (const int*)d_in[2];
  const float* emb = (const float*)d_in[3];
  const float* W1l = (const float*)d_in[4];
  const float* b1 = (const float*)d_in[5];
  const float* W1r = (const float*)d_in[6];
  const float* W2l = (const float*)d_in[7];
  const float* b2 = (const float*)d_in[8];
  const float* W2r = (const float*)d_in[9];
  const float* Wout = (const float*)d_in[10];
  const float* bout = (const float*)d_in[11];
  float* out = (float*)d_out;

  int n_nodes = in_sizes[0];
  int n_edges = in_sizes[1] / 2;
  int n_graphs = out_size / 2;
  const int* src = ei;
  const int* dst = ei + n_edges;

  // bump-allocate workspace (~130 MB)
  char* p = (char*)d_ws;
  auto alloc = [&](size_t bytes) -> void* {
    void* r = (void*)p;
    p += (bytes + 255) & ~(size_t)255;
    return r;
  };
  float* h_a = (float*)alloc((size_t)n_nodes * 64 * 4);
  float* h_b = (float*)alloc((size_t)n_nodes * 64 * 4);
  int* csr = (int*)alloc((size_t)n_edges * 4);
  int* cnt = (int*)alloc((size_t)n_nodes * 4);
  int* offs = (int*)alloc((size_t)(n_nodes + 1) * 4);
  int* cursor = (int*)alloc((size_t)n_nodes * 4);
  int* bsums = (int*)alloc(1024 * 4);
  int* goffs = (int*)alloc((size_t)(n_graphs + 1) * 4);
  float* wt = (float*)alloc(4 * 4096 * 4);

  hipMemsetAsync(cnt, 0, (size_t)n_nodes * 4, stream);

  k_embed<<<(n_nodes * 64 + 255) / 256, 256, 0, stream>>>(x, emb, h_a, n_nodes);
  k_hist<<<(n_edges + 255) / 256, 256, 0, stream>>>(dst, cnt, n_edges);

  int scan_blocks = (n_nodes + 1023) / 1024;  // 196 <= 256 (required by k_scan2)
  k_scan1<<<scan_blocks, 256, 0, stream>>>(cnt, offs, bsums, n_nodes);
  k_scan2<<<1, 256, 0, stream>>>(bsums, scan_blocks);
  k_scan3<<<(n_nodes + 255) / 256, 256, 0, stream>>>(offs, bsums, n_nodes, n_edges);
  hipMemcpyAsync(cursor, offs, (size_t)n_nodes * 4, hipMemcpyDeviceToDevice, stream);
  k_fill<<<(n_edges + 255) / 256, 256, 0, stream>>>(src, dst, cursor, csr, n_edges);

  k_transpose4<<<4, 256, 0, stream>>>(W1l, W1r, W2l, W2r, wt);
  k_goffs<<<(n_nodes + 255) / 256, 256, 0, stream>>>(batch, goffs, n_nodes, n_graphs);

  k_sage<<<(n_nodes + NPB - 1) / NPB, 64 * NPB, 0, stream>>>(h_a, h_b, offs, csr, wt, wt + 4096, b1, n_nodes);
  k_sage<<<(n_nodes + NPB - 1) / NPB, 64 * NPB, 0, stream>>>(h_b, h_a, offs, csr, wt + 8192, wt + 12288, b2, n_nodes);

  k_poolout<<<(n_graphs + NPB - 1) / NPB, 64 * NPB, 0, stream>>>(h_a, goffs, Wout, bout, out, n_graphs);
}

// Round 2
// 919.078 us; speedup vs baseline: 1.7174x; 1.7174x over previous
//
#include <hip/hip_runtime.h>
#include <stdint.h>

// GNN: h=emb[x]; 2x SAGEConv(mean)+ReLU; global_mean_pool (sorted batch); linear -> [G,2]
// CSR build: bucketed two-pass counting sort to avoid scatter write-amplification.

#define NPB 4       // waves per block in conv/pool kernels
#define NBUCK 256   // dst buckets; bucket csr window ~100KB -> L2-resident
#define TILE 4096   // edges per partition tile
#define EPT 16      // TILE / 256 threads
#define MAXN 1024   // >= ceil(n_nodes / NBUCK)

__device__ __forceinline__ int bucket_of(int dstv, int n_nodes) {
  return (int)(((unsigned long long)(unsigned)dstv * NBUCK) / (unsigned)n_nodes);
}

__global__ void k_embed(const int* __restrict__ x, const float* __restrict__ emb,
                        float* __restrict__ h, int n_nodes) {
  int gid = blockIdx.x * blockDim.x + threadIdx.x;
  if (gid >= n_nodes * 64) return;
  int node = gid >> 6, f = gid & 63;
  h[gid] = emb[(size_t)x[node] * 64 + f];
}

// per-bucket edge totals via LDS histogram (blockDim must be 256 == NBUCK)
__global__ void k_bhist(const int* __restrict__ dst, int* __restrict__ btot,
                        int n_edges, int n_nodes) {
  __shared__ int h[NBUCK];
  int t = threadIdx.x;
  h[t] = 0;
  __syncthreads();
  int stride = gridDim.x * blockDim.x;
  for (int e = blockIdx.x * blockDim.x + t; e < n_edges; e += stride)
    atomicAdd(&h[bucket_of(dst[e], n_nodes)], 1);
  __syncthreads();
  if (h[t]) atomicAdd(&btot[t], h[t]);
}

// exclusive scan of 256 bucket totals -> bbase (immutable) + gcur (partition cursors)
__global__ void k_bscan(const int* __restrict__ btot, int* __restrict__ bbase,
                        int* __restrict__ gcur, int n_edges) {
  __shared__ int s[NBUCK];
  int t = threadIdx.x;
  s[t] = btot[t];
  __syncthreads();
  for (int off = 1; off < NBUCK; off <<= 1) {
    int add = (t >= off) ? s[t - off] : 0;
    __syncthreads();
    s[t] += add;
    __syncthreads();
  }
  int excl = (t == 0) ? 0 : s[t - 1];
  bbase[t] = excl;
  gcur[t] = excl;
  if (t == NBUCK - 1) bbase[NBUCK] = n_edges;
}

// LDS-tile multisplit: scatter (src,dst) pairs into bucket-contiguous regions.
// Per tile, each bucket receives a dense private ~128B run -> full-line writes.
__global__ void k_part(const int* __restrict__ src, const int* __restrict__ dst,
                       int* __restrict__ gcur, uint2* __restrict__ pairs,
                       int n_edges, int n_nodes, int chunk) {
  __shared__ int hist[NBUCK];
  __shared__ int base[NBUCK];
  int t = threadIdx.x;
  int beg = blockIdx.x * chunk;
  int end = min(beg + chunk, n_edges);
  for (int tbeg = beg; tbeg < end; tbeg += TILE) {
    int cnt = min(TILE, end - tbeg);
    hist[t] = 0;
    __syncthreads();
    int s[EPT], d[EPT], r[EPT], bk[EPT];
    bool v[EPT];
#pragma unroll
    for (int k = 0; k < EPT; ++k) {
      int li = k * 256 + t;
      v[k] = li < cnt;
      if (v[k]) {
        int i = tbeg + li;
        s[k] = src[i];
        d[k] = dst[i];
        bk[k] = bucket_of(d[k], n_nodes);
        r[k] = atomicAdd(&hist[bk[k]], 1);
      }
    }
    __syncthreads();
    base[t] = (hist[t] > 0) ? atomicAdd(&gcur[t], hist[t]) : 0;
    __syncthreads();
#pragma unroll
    for (int k = 0; k < EPT; ++k)
      if (v[k]) pairs[base[bk[k]] + r[k]] = make_uint2((unsigned)s[k], (unsigned)d[k]);
    __syncthreads();
  }
}

// one block per bucket: LDS node-histogram -> block scan -> offs[]; then scatter
// src into the bucket's ~100KB csr window (single block/XCD -> L2-resident, dense).
__global__ void k_bucket(const uint2* __restrict__ pairs, const int* __restrict__ bbase,
                         int* __restrict__ offs, int* __restrict__ csr,
                         int n_nodes, int n_edges) {
  __shared__ int lcnt[MAXN];
  __shared__ int lcur[MAXN];
  __shared__ int stmp[256];
  int b = blockIdx.x, t = threadIdx.x;
  int nb0 = (int)(((long long)b * n_nodes + NBUCK - 1) / NBUCK);
  int nb1 = (int)(((long long)(b + 1) * n_nodes + NBUCK - 1) / NBUCK);
  int nn = nb1 - nb0;
  int ebeg = bbase[b], eend = bbase[b + 1];
  for (int i = t; i < nn; i += 256) lcnt[i] = 0;
  __syncthreads();
  for (int i = ebeg + t; i < eend; i += 256)
    atomicAdd(&lcnt[(int)pairs[i].y - nb0], 1);
  __syncthreads();
  // exclusive scan of lcnt[0..nn) (nn <= 1024), 4 items/thread
  int i0 = t * 4;
  int v0 = (i0 + 0 < nn) ? lcnt[i0 + 0] : 0;
  int v1 = (i0 + 1 < nn) ? lcnt[i0 + 1] : 0;
  int v2 = (i0 + 2 < nn) ? lcnt[i0 + 2] : 0;
  int v3 = (i0 + 3 < nn) ? lcnt[i0 + 3] : 0;
  stmp[t] = v0 + v1 + v2 + v3;
  __syncthreads();
  for (int off = 1; off < 256; off <<= 1) {
    int add = (t >= off) ? stmp[t - off] : 0;
    __syncthreads();
    stmp[t] += add;
    __syncthreads();
  }
  int run = ebeg + ((t == 0) ? 0 : stmp[t - 1]);
  if (i0 + 0 < nn) { lcur[i0 + 0] = run; offs[nb0 + i0 + 0] = run; run += v0; }
  if (i0 + 1 < nn) { lcur[i0 + 1] = run; offs[nb0 + i0 + 1] = run; run += v1; }
  if (i0 + 2 < nn) { lcur[i0 + 2] = run; offs[nb0 + i0 + 2] = run; run += v2; }
  if (i0 + 3 < nn) { lcur[i0 + 3] = run; offs[nb0 + i0 + 3] = run; run += v3; }
  if (b == NBUCK - 1 && t == 0) offs[n_nodes] = n_edges;
  __syncthreads();
  for (int i = ebeg + t; i < eend; i += 256) {
    uint2 e = pairs[i];
    int pos = atomicAdd(&lcur[(int)e.y - nb0], 1);
    csr[pos] = (int)e.x;
  }
}

__global__ void k_transpose4(const float* __restrict__ a0, const float* __restrict__ a1,
                             const float* __restrict__ a2, const float* __restrict__ a3,
                             float* __restrict__ wt) {
  const float* s = (blockIdx.x == 0) ? a0 : (blockIdx.x == 1) ? a1 : (blockIdx.x == 2) ? a2 : a3;
  float* d = wt + blockIdx.x * 4096;
  for (int i = threadIdx.x; i < 4096; i += blockDim.x) {
    int r = i >> 6, c = i & 63;
    d[c * 64 + r] = s[i];
  }
}

// one wave per node; lane = feature. mean-aggregate then relu(mean@WlT + self@WrT + b)
__global__ void k_sage(const float* __restrict__ hin, float* __restrict__ hout,
                       const int* __restrict__ offs, const int* __restrict__ csr,
                       const float* __restrict__ wlT, const float* __restrict__ wrT,
                       const float* __restrict__ bias, int n_nodes) {
  __shared__ float sm[NPB][64];
  __shared__ float ss[NPB][64];
  int wid = threadIdx.x >> 6, lane = threadIdx.x & 63;
  int node = blockIdx.x * NPB + wid;
  bool active = node < n_nodes;
  if (active) {
    int beg = offs[node], end = offs[node + 1];
    float a0 = 0.f, a1 = 0.f, a2 = 0.f, a3 = 0.f;
    int j = beg;
    for (; j + 3 < end; j += 4) {
      int s0 = csr[j], s1 = csr[j + 1], s2 = csr[j + 2], s3 = csr[j + 3];
      a0 += hin[(size_t)s0 * 64 + lane];
      a1 += hin[(size_t)s1 * 64 + lane];
      a2 += hin[(size_t)s2 * 64 + lane];
      a3 += hin[(size_t)s3 * 64 + lane];
    }
    for (; j < end; ++j) a0 += hin[(size_t)csr[j] * 64 + lane];
    float sum = (a0 + a1) + (a2 + a3);
    int deg = end - beg;
    sm[wid][lane] = (deg > 0) ? sum / (float)deg : 0.f;
    ss[wid][lane] = hin[(size_t)node * 64 + lane];
  }
  __syncthreads();
  if (active) {
    float out = bias[lane];
    const float* m = sm[wid];
    const float* s = ss[wid];
#pragma unroll 8
    for (int f = 0; f < 64; ++f) {
      out = fmaf(m[f], wlT[f * 64 + lane], out);
      out = fmaf(s[f], wrT[f * 64 + lane], out);
    }
    hout[(size_t)node * 64 + lane] = fmaxf(out, 0.f);
  }
}

__global__ void k_goffs(const int* __restrict__ batch, int* __restrict__ goffs,
                        int n_nodes, int n_graphs) {
  int i = blockIdx.x * blockDim.x + threadIdx.x;
  if (i >= n_nodes) return;
  int b = batch[i];
  int bp = (i == 0) ? -1 : batch[i - 1];
  for (int g = bp + 1; g <= b; ++g) goffs[g] = i;
  if (i == n_nodes - 1)
    for (int g = b + 1; g <= n_graphs; ++g) goffs[g] = n_nodes;
}

__global__ void k_poolout(const float* __restrict__ h, const int* __restrict__ goffs,
                          const float* __restrict__ wout, const float* __restrict__ bout,
                          float* __restrict__ out, int n_graphs) {
  int wid = threadIdx.x >> 6, lane = threadIdx.x & 63;
  int g = blockIdx.x * NPB + wid;
  if (g >= n_graphs) return;
  int beg = goffs[g], end = goffs[g + 1];
  float a0 = 0.f, a1 = 0.f, a2 = 0.f, a3 = 0.f;
  int n = beg;
  for (; n + 3 < end; n += 4) {
    a0 += h[(size_t)n * 64 + lane];
    a1 += h[(size_t)(n + 1) * 64 + lane];
    a2 += h[(size_t)(n + 2) * 64 + lane];
    a3 += h[(size_t)(n + 3) * 64 + lane];
  }
  for (; n < end; ++n) a0 += h[(size_t)n * 64 + lane];
  float sum = (a0 + a1) + (a2 + a3);
  int cnt = end - beg;
  float mean = (cnt > 0) ? sum / (float)cnt : 0.f;
  float p0 = mean * wout[lane];
  float p1 = mean * wout[64 + lane];
  for (int o = 32; o > 0; o >>= 1) {
    p0 += __shfl_down(p0, o);
    p1 += __shfl_down(p1, o);
  }
  if (lane == 0) {
    out[g * 2 + 0] = p0 + bout[0];
    out[g * 2 + 1] = p1 + bout[1];
  }
}

extern "C" void kernel_launch(void* const* d_in, const int* in_sizes, int n_in,
                              void* d_out, int out_size, void* d_ws, size_t ws_size,
                              hipStream_t stream) {
  const int* x = (const int*)d_in[0];
  const int* ei = (const int*)d_in[1];
  const int* batch = (const int*)d_in[2];
  const float* emb = (const float*)d_in[3];
  const float* W1l = (const float*)d_in[4];
  const float* b1 = (const float*)d_in[5];
  const float* W1r = (const float*)d_in[6];
  const float* W2l = (const float*)d_in[7];
  const float* b2 = (const float*)d_in[8];
  const float* W2r = (const float*)d_in[9];
  const float* Wout = (const float*)d_in[10];
  const float* bout = (const float*)d_in[11];
  float* out = (float*)d_out;

  int n_nodes = in_sizes[0];
  int n_edges = in_sizes[1] / 2;
  int n_graphs = out_size / 2;
  const int* src = ei;
  const int* dst = ei + n_edges;

  char* p = (char*)d_ws;
  auto alloc = [&](size_t bytes) -> void* {
    void* r = (void*)p;
    p += (bytes + 255) & ~(size_t)255;
    return r;
  };
  size_t hbytes = (size_t)n_nodes * 64 * 4;
  size_t pbytes = (size_t)n_edges * 8;
  float* h_a = (float*)alloc(hbytes);
  float* h_b = (float*)alloc(hbytes > pbytes ? hbytes : pbytes);  // aliased with pairs
  int* csr = (int*)alloc((size_t)n_edges * 4);
  int* offs = (int*)alloc((size_t)(n_nodes + 1) * 4);
  int* btot = (int*)alloc(NBUCK * 4);
  int* bbase = (int*)alloc((NBUCK + 1) * 4);
  int* gcur = (int*)alloc(NBUCK * 4);
  int* goffs = (int*)alloc((size_t)(n_graphs + 1) * 4);
  float* wt = (float*)alloc(4 * 4096 * 4);
  uint2* pairs = (uint2*)h_b;  // pairs dead before k_sage writes h_b

  hipMemsetAsync(btot, 0, NBUCK * 4, stream);

  k_embed<<<(n_nodes * 64 + 255) / 256, 256, 0, stream>>>(x, emb, h_a, n_nodes);

  k_bhist<<<1024, 256, 0, stream>>>(dst, btot, n_edges, n_nodes);
  k_bscan<<<1, NBUCK, 0, stream>>>(btot, bbase, gcur, n_edges);
  int part_blocks = 512;
  int chunk = (n_edges + part_blocks - 1) / part_blocks;
  k_part<<<part_blocks, 256, 0, stream>>>(src, dst, gcur, pairs, n_edges, n_nodes, chunk);
  k_bucket<<<NBUCK, 256, 0, stream>>>(pairs, bbase, offs, csr, n_nodes, n_edges);

  k_transpose4<<<4, 256, 0, stream>>>(W1l, W1r, W2l, W2r, wt);
  k_goffs<<<(n_nodes + 255) / 256, 256, 0, stream>>>(batch, goffs, n_nodes, n_graphs);

  k_sage<<<(n_nodes + NPB - 1) / NPB, 64 * NPB, 0, stream>>>(h_a, h_b, offs, csr, wt, wt + 4096, b1, n_nodes);
  k_sage<<<(n_nodes + NPB - 1) / NPB, 64 * NPB, 0, stream>>>(h_b, h_a, offs, csr, wt + 8192, wt + 12288, b2, n_nodes);

  k_poolout<<<(n_graphs + NPB - 1) / NPB, 64 * NPB, 0, stream>>>(h_a, goffs, Wout, bout, out, n_graphs);
}

// Round 3
// 875.519 us; speedup vs baseline: 1.8029x; 1.0498x over previous
//
#include <hip/hip_runtime.h>
#include <hip/hip_fp16.h>
#include <stdint.h>

// GNN: 2x SAGEConv(mean)+ReLU + mean-pool + linear, algebraically refactored:
//  te = emb@W1l^T (L2-resident gather table), trb = emb@W1r^T + b1
//  conv1: h1 = relu(mean(te[vx]) + trb[x[n]]); g1 = h1@W2l^T (fp16, gathered by conv2);
//         s1 = h1@W2r^T + b2 (fp32)
//  conv2: h2 = relu(mean(g1[src]) + s1[n]); o[n] = h2@Wout^T (2 floats)
//  pool:  out[g] = mean(o) + bout

#define NPB 4       // waves per block in conv/pool kernels
#define NBUCK 256   // dst buckets
#define TILE 4096   // edges per partition tile
#define EPT 16      // TILE / 256
#define MAXN 1024   // >= ceil(n_nodes / NBUCK)

__device__ __forceinline__ int bucket_of(int dstv, int n_nodes) {
  return (int)(((unsigned)dstv * 256u) / (unsigned)n_nodes);  // NBUCK=256
}

// per-bucket edge totals via LDS histogram (blockDim == 256 == NBUCK)
__global__ void k_bhist(const int* __restrict__ dst, int* __restrict__ btot,
                        int n_edges, int n_nodes) {
  __shared__ int h[NBUCK];
  int t = threadIdx.x;
  h[t] = 0;
  __syncthreads();
  int stride = gridDim.x * blockDim.x;
  for (int e = blockIdx.x * blockDim.x + t; e < n_edges; e += stride)
    atomicAdd(&h[bucket_of(dst[e], n_nodes)], 1);
  __syncthreads();
  if (h[t]) atomicAdd(&btot[t], h[t]);
}

__global__ void k_bscan(const int* __restrict__ btot, int* __restrict__ bbase,
                        int* __restrict__ gcur, int n_edges) {
  __shared__ int s[NBUCK];
  int t = threadIdx.x;
  s[t] = btot[t];
  __syncthreads();
  for (int off = 1; off < NBUCK; off <<= 1) {
    int add = (t >= off) ? s[t - off] : 0;
    __syncthreads();
    s[t] += add;
    __syncthreads();
  }
  int excl = (t == 0) ? 0 : s[t - 1];
  bbase[t] = excl;
  gcur[t] = excl;
  if (t == NBUCK - 1) bbase[NBUCK] = n_edges;
}

// LDS-tile multisplit: scatter packed (dloc<<18 | src) into bucket-contiguous regions
__global__ void k_part(const int* __restrict__ src, const int* __restrict__ dst,
                       int* __restrict__ gcur, unsigned* __restrict__ pairs,
                       int n_edges, int n_nodes, int chunk) {
  __shared__ int hist[NBUCK];
  __shared__ int base[NBUCK];
  int t = threadIdx.x;
  int beg = blockIdx.x * chunk;
  int end = min(beg + chunk, n_edges);
  for (int tbeg = beg; tbeg < end; tbeg += TILE) {
    int cnt = min(TILE, end - tbeg);
    hist[t] = 0;
    __syncthreads();
    unsigned pk[EPT];
    int r[EPT], bk[EPT];
    bool v[EPT];
#pragma unroll
    for (int k = 0; k < EPT; ++k) {
      int li = k * 256 + t;
      v[k] = li < cnt;
      if (v[k]) {
        int i = tbeg + li;
        int s = src[i];
        int d = dst[i];
        bk[k] = bucket_of(d, n_nodes);
        unsigned nb0 = ((unsigned)bk[k] * (unsigned)n_nodes + 255u) >> 8;
        pk[k] = (((unsigned)d - nb0) << 18) | (unsigned)s;
        r[k] = atomicAdd(&hist[bk[k]], 1);
      }
    }
    __syncthreads();
    base[t] = (hist[t] > 0) ? atomicAdd(&gcur[t], hist[t]) : 0;
    __syncthreads();
#pragma unroll
    for (int k = 0; k < EPT; ++k)
      if (v[k]) pairs[base[bk[k]] + r[k]] = pk[k];
    __syncthreads();
  }
}

// one block per bucket: LDS node-hist -> scan -> offs; scatter src + vx=x[src]
__global__ void k_bucket(const unsigned* __restrict__ pairs, const int* __restrict__ bbase,
                         const int* __restrict__ x, int* __restrict__ offs,
                         int* __restrict__ csr, int* __restrict__ vx,
                         int n_nodes, int n_edges) {
  __shared__ int lcnt[MAXN];
  __shared__ int lcur[MAXN];
  __shared__ int stmp[256];
  int b = blockIdx.x, t = threadIdx.x;
  int nb0 = (int)((((unsigned)b * (unsigned)n_nodes) + 255u) >> 8);
  int nb1 = (int)((((unsigned)(b + 1) * (unsigned)n_nodes) + 255u) >> 8);
  if (nb1 > n_nodes) nb1 = n_nodes;
  int nn = nb1 - nb0;
  int ebeg = bbase[b], eend = bbase[b + 1];
  for (int i = t; i < nn; i += 256) lcnt[i] = 0;
  __syncthreads();
  for (int i = ebeg + t; i < eend; i += 256)
    atomicAdd(&lcnt[pairs[i] >> 18], 1);
  __syncthreads();
  int i0 = t * 4;
  int v0 = (i0 + 0 < nn) ? lcnt[i0 + 0] : 0;
  int v1 = (i0 + 1 < nn) ? lcnt[i0 + 1] : 0;
  int v2 = (i0 + 2 < nn) ? lcnt[i0 + 2] : 0;
  int v3 = (i0 + 3 < nn) ? lcnt[i0 + 3] : 0;
  stmp[t] = v0 + v1 + v2 + v3;
  __syncthreads();
  for (int off = 1; off < 256; off <<= 1) {
    int add = (t >= off) ? stmp[t - off] : 0;
    __syncthreads();
    stmp[t] += add;
    __syncthreads();
  }
  int run = ebeg + ((t == 0) ? 0 : stmp[t - 1]);
  if (i0 + 0 < nn) { lcur[i0 + 0] = run; offs[nb0 + i0 + 0] = run; run += v0; }
  if (i0 + 1 < nn) { lcur[i0 + 1] = run; offs[nb0 + i0 + 1] = run; run += v1; }
  if (i0 + 2 < nn) { lcur[i0 + 2] = run; offs[nb0 + i0 + 2] = run; run += v2; }
  if (i0 + 3 < nn) { lcur[i0 + 3] = run; offs[nb0 + i0 + 3] = run; run += v3; }
  if (b == NBUCK - 1 && t == 0) offs[n_nodes] = n_edges;
  __syncthreads();
  for (int i = ebeg + t; i < eend; i += 256) {
    unsigned e = pairs[i];
    int s = (int)(e & 0x3FFFFu);
    int pos = atomicAdd(&lcur[e >> 18], 1);
    csr[pos] = s;
    vx[pos] = x[s];
  }
}

__global__ void k_transpose4(const float* __restrict__ a0, const float* __restrict__ a1,
                             const float* __restrict__ a2, const float* __restrict__ a3,
                             float* __restrict__ wt) {
  const float* s = (blockIdx.x == 0) ? a0 : (blockIdx.x == 1) ? a1 : (blockIdx.x == 2) ? a2 : a3;
  float* d = wt + blockIdx.x * 4096;
  for (int i = threadIdx.x; i < 4096; i += blockDim.x) {
    int r = i >> 6, c = i & 63;
    d[c * 64 + r] = s[i];
  }
}

// te = emb@W1l^T ; trb = emb@W1r^T + b1   (wave per vocab row)
__global__ void k_prep(const float* __restrict__ emb, const float* __restrict__ w1lT,
                       const float* __restrict__ w1rT, const float* __restrict__ b1,
                       float* __restrict__ te, float* __restrict__ trb, int vocab) {
  __shared__ float se[NPB][64];
  int wid = threadIdx.x >> 6, lane = threadIdx.x & 63;
  int v = blockIdx.x * NPB + wid;
  if (v >= vocab) return;
  se[wid][lane] = emb[(size_t)v * 64 + lane];
  __syncwarp();
  float aL = 0.f, aR = b1[lane];
#pragma unroll 8
  for (int f = 0; f < 64; ++f) {
    float ev = se[wid][f];
    aL = fmaf(ev, w1lT[f * 64 + lane], aL);
    aR = fmaf(ev, w1rT[f * 64 + lane], aR);
  }
  te[(size_t)v * 64 + lane] = aL;
  trb[(size_t)v * 64 + lane] = aR;
}

// conv1: gather te (L2-resident) via vx; h1=relu(mean+trb[x[n]]);
// epilogue: g1 = h1@W2l^T (fp16), s1 = h1@W2r^T + b2 (fp32)
__global__ void k_conv1(const int* __restrict__ vx, const int* __restrict__ offs,
                        const float* __restrict__ te, const float* __restrict__ trb,
                        const int* __restrict__ x, const float* __restrict__ w2lT,
                        const float* __restrict__ w2rT, const float* __restrict__ b2,
                        __half* __restrict__ g1, float* __restrict__ s1, int n_nodes) {
  __shared__ float sm[NPB][64];
  int wid = threadIdx.x >> 6, lane = threadIdx.x & 63;
  int node = blockIdx.x * NPB + wid;
  bool active = node < n_nodes;
  if (active) {
    int beg = offs[node], end = offs[node + 1];
    float a0 = 0.f, a1 = 0.f, a2 = 0.f, a3 = 0.f;
    int j = beg;
    for (; j + 3 < end; j += 4) {
      int v0 = vx[j], v1 = vx[j + 1], v2 = vx[j + 2], v3 = vx[j + 3];
      a0 += te[(size_t)v0 * 64 + lane];
      a1 += te[(size_t)v1 * 64 + lane];
      a2 += te[(size_t)v2 * 64 + lane];
      a3 += te[(size_t)v3 * 64 + lane];
    }
    for (; j < end; ++j) a0 += te[(size_t)vx[j] * 64 + lane];
    float sum = (a0 + a1) + (a2 + a3);
    int deg = end - beg;
    float mean = (deg > 0) ? sum / (float)deg : 0.f;
    float z = mean + trb[(size_t)x[node] * 64 + lane];
    sm[wid][lane] = fmaxf(z, 0.f);
  }
  __syncthreads();
  if (active) {
    float aL = 0.f, aR = b2[lane];
    const float* hrow = sm[wid];
#pragma unroll 8
    for (int f = 0; f < 64; ++f) {
      float hv = hrow[f];
      aL = fmaf(hv, w2lT[f * 64 + lane], aL);
      aR = fmaf(hv, w2rT[f * 64 + lane], aR);
    }
    g1[(size_t)node * 64 + lane] = __float2half(aL);
    s1[(size_t)node * 64 + lane] = aR;
  }
}

// conv2: gather g1 fp16; h2=relu(mean+s1[n]); o[n] = h2@Wout^T (2 floats)
__global__ void k_conv2(const int* __restrict__ csr, const int* __restrict__ offs,
                        const __half* __restrict__ g1, const float* __restrict__ s1,
                        const float* __restrict__ wout, float* __restrict__ o,
                        int n_nodes) {
  int wid = threadIdx.x >> 6, lane = threadIdx.x & 63;
  int node = blockIdx.x * NPB + wid;
  if (node >= n_nodes) return;
  int beg = offs[node], end = offs[node + 1];
  float a0 = 0.f, a1 = 0.f, a2 = 0.f, a3 = 0.f;
  int j = beg;
  for (; j + 3 < end; j += 4) {
    int s0 = csr[j], s1i = csr[j + 1], s2 = csr[j + 2], s3 = csr[j + 3];
    a0 += __half2float(g1[(size_t)s0 * 64 + lane]);
    a1 += __half2float(g1[(size_t)s1i * 64 + lane]);
    a2 += __half2float(g1[(size_t)s2 * 64 + lane]);
    a3 += __half2float(g1[(size_t)s3 * 64 + lane]);
  }
  for (; j < end; ++j) a0 += __half2float(g1[(size_t)csr[j] * 64 + lane]);
  float sum = (a0 + a1) + (a2 + a3);
  int deg = end - beg;
  float mean = (deg > 0) ? sum / (float)deg : 0.f;
  float h2 = fmaxf(mean + s1[(size_t)node * 64 + lane], 0.f);
  float p0 = h2 * wout[lane];
  float p1 = h2 * wout[64 + lane];
  for (int off = 32; off > 0; off >>= 1) {
    p0 += __shfl_down(p0, off);
    p1 += __shfl_down(p1, off);
  }
  if (lane == 0) {
    o[(size_t)node * 2 + 0] = p0;
    o[(size_t)node * 2 + 1] = p1;
  }
}

__global__ void k_goffs(const int* __restrict__ batch, int* __restrict__ goffs,
                        int n_nodes, int n_graphs) {
  int i = blockIdx.x * blockDim.x + threadIdx.x;
  if (i >= n_nodes) return;
  int b = batch[i];
  int bp = (i == 0) ? -1 : batch[i - 1];
  for (int g = bp + 1; g <= b; ++g) goffs[g] = i;
  if (i == n_nodes - 1)
    for (int g = b + 1; g <= n_graphs; ++g) goffs[g] = n_nodes;
}

// wave per graph: mean of per-node logits + bout
__global__ void k_pool(const float2* __restrict__ o, const int* __restrict__ goffs,
                       const float* __restrict__ bout, float* __restrict__ out,
                       int n_graphs) {
  int wid = threadIdx.x >> 6, lane = threadIdx.x & 63;
  int g = blockIdx.x * NPB + wid;
  if (g >= n_graphs) return;
  int beg = goffs[g], end = goffs[g + 1];
  float a0 = 0.f, a1 = 0.f;
  for (int n = beg + lane; n < end; n += 64) {
    float2 v = o[n];
    a0 += v.x;
    a1 += v.y;
  }
  for (int off = 32; off > 0; off >>= 1) {
    a0 += __shfl_down(a0, off);
    a1 += __shfl_down(a1, off);
  }
  if (lane == 0) {
    int cnt = end - beg;
    float inv = (cnt > 0) ? 1.f / (float)cnt : 0.f;
    out[g * 2 + 0] = a0 * inv + bout[0];
    out[g * 2 + 1] = a1 * inv + bout[1];
  }
}

extern "C" void kernel_launch(void* const* d_in, const int* in_sizes, int n_in,
                              void* d_out, int out_size, void* d_ws, size_t ws_size,
                              hipStream_t stream) {
  const int* x = (const int*)d_in[0];
  const int* ei = (const int*)d_in[1];
  const int* batch = (const int*)d_in[2];
  const float* emb = (const float*)d_in[3];
  const float* W1l = (const float*)d_in[4];
  const float* b1 = (const float*)d_in[5];
  const float* W1r = (const float*)d_in[6];
  const float* W2l = (const float*)d_in[7];
  const float* b2 = (const float*)d_in[8];
  const float* W2r = (const float*)d_in[9];
  const float* Wout = (const float*)d_in[10];
  const float* bout = (const float*)d_in[11];
  float* out = (float*)d_out;

  int n_nodes = in_sizes[0];
  int n_edges = in_sizes[1] / 2;
  int vocab = in_sizes[3] / 64;
  int n_graphs = out_size / 2;
  const int* src = ei;
  const int* dst = ei + n_edges;

  char* p = (char*)d_ws;
  auto alloc = [&](size_t bytes) -> void* {
    void* r = (void*)p;
    p += (bytes + 255) & ~(size_t)255;
    return r;
  };
  float* te = (float*)alloc((size_t)vocab * 64 * 4);
  float* trb = (float*)alloc((size_t)vocab * 64 * 4);
  float* wt = (float*)alloc(4 * 4096 * 4);
  int* offs = (int*)alloc((size_t)(n_nodes + 1) * 4);
  int* goffs = (int*)alloc((size_t)(n_graphs + 1) * 4);
  int* btot = (int*)alloc(NBUCK * 4);
  int* bbase = (int*)alloc((NBUCK + 1) * 4);
  int* gcur = (int*)alloc(NBUCK * 4);
  int* csr = (int*)alloc((size_t)n_edges * 4);
  int* vx = (int*)alloc((size_t)n_edges * 4);
  unsigned* pairs = (unsigned*)alloc((size_t)n_edges * 4);  // reused as g1 after k_bucket
  float* s1 = (float*)alloc((size_t)n_nodes * 64 * 4);
  float* o = (float*)alloc((size_t)n_nodes * 2 * 4);
  __half* g1 = (__half*)pairs;  // pairs dead before k_conv1 writes g1

  hipMemsetAsync(btot, 0, NBUCK * 4, stream);

  k_transpose4<<<4, 256, 0, stream>>>(W1l, W1r, W2l, W2r, wt);
  k_prep<<<(vocab + NPB - 1) / NPB, 64 * NPB, 0, stream>>>(emb, wt, wt + 4096, b1, te, trb, vocab);

  k_bhist<<<1024, 256, 0, stream>>>(dst, btot, n_edges, n_nodes);
  k_bscan<<<1, NBUCK, 0, stream>>>(btot, bbase, gcur, n_edges);
  int part_blocks = 512;
  int chunk = (n_edges + part_blocks - 1) / part_blocks;
  k_part<<<part_blocks, 256, 0, stream>>>(src, dst, gcur, pairs, n_edges, n_nodes, chunk);
  k_bucket<<<NBUCK, 256, 0, stream>>>(pairs, bbase, x, offs, csr, vx, n_nodes, n_edges);

  k_goffs<<<(n_nodes + 255) / 256, 256, 0, stream>>>(batch, goffs, n_nodes, n_graphs);

  k_conv1<<<(n_nodes + NPB - 1) / NPB, 64 * NPB, 0, stream>>>(vx, offs, te, trb, x, wt + 8192, wt + 12288, b2, g1, s1, n_nodes);
  k_conv2<<<(n_nodes + NPB - 1) / NPB, 64 * NPB, 0, stream>>>(csr, offs, g1, s1, Wout, o, n_nodes);
  k_pool<<<(n_graphs + NPB - 1) / NPB, 64 * NPB, 0, stream>>>((const float2*)o, goffs, bout, out, n_graphs);
}

// Round 4
// 656.484 us; speedup vs baseline: 2.4044x; 1.3336x over previous
//
#include <hip/hip_runtime.h>
#include <hip/hip_fp16.h>
#include <stdint.h>

// GNN: 2x SAGEConv(mean)+ReLU + mean-pool + linear, algebraically refactored:
//  te = emb@W1l^T (L2-resident gather table), trb = emb@W1r^T + b1
//  conv1: h1 = relu(mean(te[x[src]]) + trb[x[n]]); g1 = h1@W2l^T (fp16); s1 = h1@W2r^T + b2
//  conv2: h2 = relu(mean(g1[src]) + s1[n]); o[n] = h2@Wout^T
//  pool:  out[g] = mean(o) + bout
// Edge indices packed: idx[pos] = (x[src]<<18) | src  (vocab<2^14, n_nodes<2^18).
// Convs gather 4 (fp32) / 8 (fp16) rows per wave-load: 16B/lane, subrow-split wave.

#define NPB 4       // waves per block in conv/pool kernels
#define NBUCK 256   // dst buckets
#define TILE 4096   // edges per partition tile
#define EPT 16      // TILE / 256
#define MAXN 1024   // >= ceil(n_nodes / NBUCK)

__device__ __forceinline__ int bucket_of(int dstv, int n_nodes) {
  return (int)(((unsigned)dstv * 256u) / (unsigned)n_nodes);  // NBUCK=256
}

__global__ void k_bhist(const int* __restrict__ dst, int* __restrict__ btot,
                        int n_edges, int n_nodes) {
  __shared__ int h[NBUCK];
  int t = threadIdx.x;
  h[t] = 0;
  __syncthreads();
  int stride = gridDim.x * blockDim.x;
  for (int e = blockIdx.x * blockDim.x + t; e < n_edges; e += stride)
    atomicAdd(&h[bucket_of(dst[e], n_nodes)], 1);
  __syncthreads();
  if (h[t]) atomicAdd(&btot[t], h[t]);
}

__global__ void k_bscan(const int* __restrict__ btot, int* __restrict__ bbase,
                        int* __restrict__ gcur, int n_edges) {
  __shared__ int s[NBUCK];
  int t = threadIdx.x;
  s[t] = btot[t];
  __syncthreads();
  for (int off = 1; off < NBUCK; off <<= 1) {
    int add = (t >= off) ? s[t - off] : 0;
    __syncthreads();
    s[t] += add;
    __syncthreads();
  }
  int excl = (t == 0) ? 0 : s[t - 1];
  bbase[t] = excl;
  gcur[t] = excl;
  if (t == NBUCK - 1) bbase[NBUCK] = n_edges;
}

// LDS-tile multisplit: scatter packed (dloc<<18 | src) into bucket-contiguous regions
__global__ void k_part(const int* __restrict__ src, const int* __restrict__ dst,
                       int* __restrict__ gcur, unsigned* __restrict__ pairs,
                       int n_edges, int n_nodes, int chunk) {
  __shared__ int hist[NBUCK];
  __shared__ int base[NBUCK];
  int t = threadIdx.x;
  int beg = blockIdx.x * chunk;
  int end = min(beg + chunk, n_edges);
  for (int tbeg = beg; tbeg < end; tbeg += TILE) {
    int cnt = min(TILE, end - tbeg);
    hist[t] = 0;
    __syncthreads();
    unsigned pk[EPT];
    int r[EPT], bk[EPT];
    bool v[EPT];
#pragma unroll
    for (int k = 0; k < EPT; ++k) {
      int li = k * 256 + t;
      v[k] = li < cnt;
      if (v[k]) {
        int i = tbeg + li;
        int s = src[i];
        int d = dst[i];
        bk[k] = bucket_of(d, n_nodes);
        unsigned nb0 = ((unsigned)bk[k] * (unsigned)n_nodes + 255u) >> 8;
        pk[k] = (((unsigned)d - nb0) << 18) | (unsigned)s;
        r[k] = atomicAdd(&hist[bk[k]], 1);
      }
    }
    __syncthreads();
    base[t] = (hist[t] > 0) ? atomicAdd(&gcur[t], hist[t]) : 0;
    __syncthreads();
#pragma unroll
    for (int k = 0; k < EPT; ++k)
      if (v[k]) pairs[base[bk[k]] + r[k]] = pk[k];
    __syncthreads();
  }
}

// one block per bucket: LDS node-hist -> scan -> offs; scatter packed (x[src]<<18|src)
__global__ void k_bucket(const unsigned* __restrict__ pairs, const int* __restrict__ bbase,
                         const int* __restrict__ x, int* __restrict__ offs,
                         unsigned* __restrict__ idx, int n_nodes, int n_edges) {
  __shared__ int lcnt[MAXN];
  __shared__ int lcur[MAXN];
  __shared__ int stmp[256];
  int b = blockIdx.x, t = threadIdx.x;
  int nb0 = (int)((((unsigned)b * (unsigned)n_nodes) + 255u) >> 8);
  int nb1 = (int)((((unsigned)(b + 1) * (unsigned)n_nodes) + 255u) >> 8);
  if (nb1 > n_nodes) nb1 = n_nodes;
  int nn = nb1 - nb0;
  int ebeg = bbase[b], eend = bbase[b + 1];
  for (int i = t; i < nn; i += 256) lcnt[i] = 0;
  __syncthreads();
  for (int i = ebeg + t; i < eend; i += 256)
    atomicAdd(&lcnt[pairs[i] >> 18], 1);
  __syncthreads();
  int i0 = t * 4;
  int v0 = (i0 + 0 < nn) ? lcnt[i0 + 0] : 0;
  int v1 = (i0 + 1 < nn) ? lcnt[i0 + 1] : 0;
  int v2 = (i0 + 2 < nn) ? lcnt[i0 + 2] : 0;
  int v3 = (i0 + 3 < nn) ? lcnt[i0 + 3] : 0;
  stmp[t] = v0 + v1 + v2 + v3;
  __syncthreads();
  for (int off = 1; off < 256; off <<= 1) {
    int add = (t >= off) ? stmp[t - off] : 0;
    __syncthreads();
    stmp[t] += add;
    __syncthreads();
  }
  int run = ebeg + ((t == 0) ? 0 : stmp[t - 1]);
  if (i0 + 0 < nn) { lcur[i0 + 0] = run; offs[nb0 + i0 + 0] = run; run += v0; }
  if (i0 + 1 < nn) { lcur[i0 + 1] = run; offs[nb0 + i0 + 1] = run; run += v1; }
  if (i0 + 2 < nn) { lcur[i0 + 2] = run; offs[nb0 + i0 + 2] = run; run += v2; }
  if (i0 + 3 < nn) { lcur[i0 + 3] = run; offs[nb0 + i0 + 3] = run; run += v3; }
  if (b == NBUCK - 1 && t == 0) offs[n_nodes] = n_edges;
  __syncthreads();
  for (int i = ebeg + t; i < eend; i += 256) {
    unsigned e = pairs[i];
    int s = (int)(e & 0x3FFFFu);
    int pos = atomicAdd(&lcur[e >> 18], 1);
    idx[pos] = ((unsigned)x[s] << 18) | (unsigned)s;
  }
}

__global__ void k_transpose4(const float* __restrict__ a0, const float* __restrict__ a1,
                             const float* __restrict__ a2, const float* __restrict__ a3,
                             float* __restrict__ wt) {
  const float* s = (blockIdx.x == 0) ? a0 : (blockIdx.x == 1) ? a1 : (blockIdx.x == 2) ? a2 : a3;
  float* d = wt + blockIdx.x * 4096;
  for (int i = threadIdx.x; i < 4096; i += blockDim.x) {
    int r = i >> 6, c = i & 63;
    d[c * 64 + r] = s[i];
  }
}

// te = emb@W1l^T ; trb = emb@W1r^T + b1   (wave per vocab row)
__global__ void k_prep(const float* __restrict__ emb, const float* __restrict__ w1lT,
                       const float* __restrict__ w1rT, const float* __restrict__ b1,
                       float* __restrict__ te, float* __restrict__ trb, int vocab) {
  __shared__ float se[NPB][64];
  int wid = threadIdx.x >> 6, lane = threadIdx.x & 63;
  int v = blockIdx.x * NPB + wid;
  if (v >= vocab) return;
  se[wid][lane] = emb[(size_t)v * 64 + lane];
  __syncwarp();
  float aL = 0.f, aR = b1[lane];
#pragma unroll 8
  for (int f = 0; f < 64; ++f) {
    float ev = se[wid][f];
    aL = fmaf(ev, w1lT[f * 64 + lane], aL);
    aR = fmaf(ev, w1rT[f * 64 + lane], aR);
  }
  te[(size_t)v * 64 + lane] = aL;
  trb[(size_t)v * 64 + lane] = aR;
}

// conv1: gather te rows (fp32, 256B) 4-per-wave-load; epilogue g1(fp16), s1(fp32)
__global__ void k_conv1(const unsigned* __restrict__ idx, const int* __restrict__ offs,
                        const float* __restrict__ te, const float* __restrict__ trb,
                        const int* __restrict__ x, const float* __restrict__ w2lT,
                        const float* __restrict__ w2rT, const float* __restrict__ b2,
                        __half* __restrict__ g1, float* __restrict__ s1, int n_nodes) {
  __shared__ float sm[NPB][64];
  int wid = threadIdx.x >> 6, lane = threadIdx.x & 63;
  int r = lane >> 4, s4 = (lane & 15) << 2;
  int node = blockIdx.x * NPB + wid;
  bool active = node < n_nodes;
  if (active) {
    int beg = offs[node], end = offs[node + 1];
    float4 a0 = make_float4(0.f, 0.f, 0.f, 0.f);
    float4 a1 = make_float4(0.f, 0.f, 0.f, 0.f);
    for (int j = beg; j < end; j += 8) {
      int j0 = j + r, j1 = j + 4 + r;
      if (j0 < end) {
        int v = (int)(idx[j0] >> 18);
        float4 t = *(const float4*)(te + ((size_t)v << 6) + s4);
        a0.x += t.x; a0.y += t.y; a0.z += t.z; a0.w += t.w;
      }
      if (j1 < end) {
        int v = (int)(idx[j1] >> 18);
        float4 t = *(const float4*)(te + ((size_t)v << 6) + s4);
        a1.x += t.x; a1.y += t.y; a1.z += t.z; a1.w += t.w;
      }
    }
    a0.x += a1.x; a0.y += a1.y; a0.z += a1.z; a0.w += a1.w;
    // sum over 4 subrows (lane bits 4,5)
    a0.x += __shfl_xor(a0.x, 16); a0.y += __shfl_xor(a0.y, 16);
    a0.z += __shfl_xor(a0.z, 16); a0.w += __shfl_xor(a0.w, 16);
    a0.x += __shfl_xor(a0.x, 32); a0.y += __shfl_xor(a0.y, 32);
    a0.z += __shfl_xor(a0.z, 32); a0.w += __shfl_xor(a0.w, 32);
    int deg = end - beg;
    float inv = (deg > 0) ? 1.f / (float)deg : 0.f;
    if (lane < 16) {
      float4 t = *(const float4*)(trb + ((size_t)x[node] << 6) + s4);
      float4 h;
      h.x = fmaxf(fmaf(a0.x, inv, t.x), 0.f);
      h.y = fmaxf(fmaf(a0.y, inv, t.y), 0.f);
      h.z = fmaxf(fmaf(a0.z, inv, t.z), 0.f);
      h.w = fmaxf(fmaf(a0.w, inv, t.w), 0.f);
      *(float4*)&sm[wid][s4] = h;
    }
  }
  __syncthreads();
  if (active) {
    float aL = 0.f, aR = b2[lane];
    const float* hrow = sm[wid];
#pragma unroll 8
    for (int f = 0; f < 64; ++f) {
      float hv = hrow[f];
      aL = fmaf(hv, w2lT[f * 64 + lane], aL);
      aR = fmaf(hv, w2rT[f * 64 + lane], aR);
    }
    g1[((size_t)node << 6) + lane] = __float2half(aL);
    s1[((size_t)node << 6) + lane] = aR;
  }
}

// conv2: gather g1 rows (fp16, 128B) 8-per-wave-load; o[n] = relu(mean+s1)@Wout^T
__global__ void k_conv2(const unsigned* __restrict__ idx, const int* __restrict__ offs,
                        const __half* __restrict__ g1, const float* __restrict__ s1,
                        const float* __restrict__ wout, float* __restrict__ o,
                        int n_nodes) {
  __shared__ float sm[NPB][64];
  int wid = threadIdx.x >> 6, lane = threadIdx.x & 63;
  int r = lane >> 3, s8 = (lane & 7) << 3;
  int node = blockIdx.x * NPB + wid;
  bool active = node < n_nodes;
  if (active) {
    int beg = offs[node], end = offs[node + 1];
    float a0[8], a1[8];
#pragma unroll
    for (int c = 0; c < 8; ++c) { a0[c] = 0.f; a1[c] = 0.f; }
    for (int j = beg; j < end; j += 16) {
      int j0 = j + r, j1 = j + 8 + r;
      if (j0 < end) {
        int sn = (int)(idx[j0] & 0x3FFFFu);
        uint4 u = *(const uint4*)(g1 + ((size_t)sn << 6) + s8);
        const __half2* hp = (const __half2*)&u;
#pragma unroll
        for (int c = 0; c < 4; ++c) {
          float2 f = __half22float2(hp[c]);
          a0[2 * c] += f.x; a0[2 * c + 1] += f.y;
        }
      }
      if (j1 < end) {
        int sn = (int)(idx[j1] & 0x3FFFFu);
        uint4 u = *(const uint4*)(g1 + ((size_t)sn << 6) + s8);
        const __half2* hp = (const __half2*)&u;
#pragma unroll
        for (int c = 0; c < 4; ++c) {
          float2 f = __half22float2(hp[c]);
          a1[2 * c] += f.x; a1[2 * c + 1] += f.y;
        }
      }
    }
#pragma unroll
    for (int c = 0; c < 8; ++c) {
      float v = a0[c] + a1[c];
      v += __shfl_xor(v, 8);
      v += __shfl_xor(v, 16);
      v += __shfl_xor(v, 32);
      a0[c] = v;
    }
    int deg = end - beg;
    float inv = (deg > 0) ? 1.f / (float)deg : 0.f;
    if (lane < 8) {
#pragma unroll
      for (int c = 0; c < 8; ++c) sm[wid][s8 + c] = a0[c] * inv;
    }
  }
  __syncthreads();
  if (active) {
    float h2 = fmaxf(sm[wid][lane] + s1[((size_t)node << 6) + lane], 0.f);
    float p0 = h2 * wout[lane];
    float p1 = h2 * wout[64 + lane];
    for (int off = 32; off > 0; off >>= 1) {
      p0 += __shfl_down(p0, off);
      p1 += __shfl_down(p1, off);
    }
    if (lane == 0) {
      o[((size_t)node << 1) + 0] = p0;
      o[((size_t)node << 1) + 1] = p1;
    }
  }
}

__global__ void k_goffs(const int* __restrict__ batch, int* __restrict__ goffs,
                        int n_nodes, int n_graphs) {
  int i = blockIdx.x * blockDim.x + threadIdx.x;
  if (i >= n_nodes) return;
  int b = batch[i];
  int bp = (i == 0) ? -1 : batch[i - 1];
  for (int g = bp + 1; g <= b; ++g) goffs[g] = i;
  if (i == n_nodes - 1)
    for (int g = b + 1; g <= n_graphs; ++g) goffs[g] = n_nodes;
}

__global__ void k_pool(const float2* __restrict__ o, const int* __restrict__ goffs,
                       const float* __restrict__ bout, float* __restrict__ out,
                       int n_graphs) {
  int wid = threadIdx.x >> 6, lane = threadIdx.x & 63;
  int g = blockIdx.x * NPB + wid;
  if (g >= n_graphs) return;
  int beg = goffs[g], end = goffs[g + 1];
  float a0 = 0.f, a1 = 0.f;
  for (int n = beg + lane; n < end; n += 64) {
    float2 v = o[n];
    a0 += v.x;
    a1 += v.y;
  }
  for (int off = 32; off > 0; off >>= 1) {
    a0 += __shfl_down(a0, off);
    a1 += __shfl_down(a1, off);
  }
  if (lane == 0) {
    int cnt = end - beg;
    float inv = (cnt > 0) ? 1.f / (float)cnt : 0.f;
    out[g * 2 + 0] = a0 * inv + bout[0];
    out[g * 2 + 1] = a1 * inv + bout[1];
  }
}

extern "C" void kernel_launch(void* const* d_in, const int* in_sizes, int n_in,
                              void* d_out, int out_size, void* d_ws, size_t ws_size,
                              hipStream_t stream) {
  const int* x = (const int*)d_in[0];
  const int* ei = (const int*)d_in[1];
  const int* batch = (const int*)d_in[2];
  const float* emb = (const float*)d_in[3];
  const float* W1l = (const float*)d_in[4];
  const float* b1 = (const float*)d_in[5];
  const float* W1r = (const float*)d_in[6];
  const float* W2l = (const float*)d_in[7];
  const float* b2 = (const float*)d_in[8];
  const float* W2r = (const float*)d_in[9];
  const float* Wout = (const float*)d_in[10];
  const float* bout = (const float*)d_in[11];
  float* out = (float*)d_out;

  int n_nodes = in_sizes[0];
  int n_edges = in_sizes[1] / 2;
  int vocab = in_sizes[3] / 64;
  int n_graphs = out_size / 2;
  const int* src = ei;
  const int* dst = ei + n_edges;

  char* p = (char*)d_ws;
  auto alloc = [&](size_t bytes) -> void* {
    void* r = (void*)p;
    p += (bytes + 255) & ~(size_t)255;
    return r;
  };
  float* te = (float*)alloc((size_t)vocab * 64 * 4);
  float* trb = (float*)alloc((size_t)vocab * 64 * 4);
  float* wt = (float*)alloc(4 * 4096 * 4);
  int* offs = (int*)alloc((size_t)(n_nodes + 1) * 4);
  int* goffs = (int*)alloc((size_t)(n_graphs + 1) * 4);
  int* btot = (int*)alloc(NBUCK * 4);
  int* bbase = (int*)alloc((NBUCK + 1) * 4);
  int* gcur = (int*)alloc(NBUCK * 4);
  unsigned* idx = (unsigned*)alloc((size_t)n_edges * 4);   // packed (x[src]<<18)|src
  unsigned* pairs = (unsigned*)alloc((size_t)n_edges * 4); // reused as g1 after k_bucket
  float* s1 = (float*)alloc((size_t)n_nodes * 64 * 4);
  float* o = (float*)alloc((size_t)n_nodes * 2 * 4);
  __half* g1 = (__half*)pairs;  // pairs dead before k_conv1 writes g1

  hipMemsetAsync(btot, 0, NBUCK * 4, stream);

  k_transpose4<<<4, 256, 0, stream>>>(W1l, W1r, W2l, W2r, wt);
  k_prep<<<(vocab + NPB - 1) / NPB, 64 * NPB, 0, stream>>>(emb, wt, wt + 4096, b1, te, trb, vocab);

  k_bhist<<<1024, 256, 0, stream>>>(dst, btot, n_edges, n_nodes);
  k_bscan<<<1, NBUCK, 0, stream>>>(btot, bbase, gcur, n_edges);
  int part_blocks = 512;
  int chunk = (n_edges + part_blocks - 1) / part_blocks;
  k_part<<<part_blocks, 256, 0, stream>>>(src, dst, gcur, pairs, n_edges, n_nodes, chunk);
  k_bucket<<<NBUCK, 256, 0, stream>>>(pairs, bbase, x, offs, idx, n_nodes, n_edges);

  k_goffs<<<(n_nodes + 255) / 256, 256, 0, stream>>>(batch, goffs, n_nodes, n_graphs);

  k_conv1<<<(n_nodes + NPB - 1) / NPB, 64 * NPB, 0, stream>>>(idx, offs, te, trb, x, wt + 8192, wt + 12288, b2, g1, s1, n_nodes);
  k_conv2<<<(n_nodes + NPB - 1) / NPB, 64 * NPB, 0, stream>>>(idx, offs, g1, s1, Wout, o, n_nodes);
  k_pool<<<(n_graphs + NPB - 1) / NPB, 64 * NPB, 0, stream>>>((const float2*)o, goffs, bout, out, n_graphs);
}

// Round 5
// 596.866 us; speedup vs baseline: 2.6445x; 1.0999x over previous
//
#include <hip/hip_runtime.h>
#include <hip/hip_fp16.h>
#include <stdint.h>

// GNN: 2x SAGEConv(mean)+ReLU + mean-pool + linear, algebraically refactored:
//  te = emb@W1l^T (L2-resident gather table), trb = emb@W1r^T + b1
//  conv1: h1 = relu(mean(te[x[src]]) + trb[x[n]]); g1 = h1@W2l^T (fp16); s1 = h1@W2r^T + b2
//  conv2: h2 = relu(mean(g1[src]) + s1[n]); o[n] = h2@Wout^T
//  pool:  out[g] = mean(o) + bout
// Edge indices packed: idx[pos] = (x[src]<<18) | src  (vocab<2^14, n_nodes<2^18).
// Convs: per 64-edge chunk, ONE coalesced idx load; row indices come from
// __shfl broadcast -> all row-gathers independent (latency-chain broken).

#define NPB 4       // waves per block in conv/pool kernels
#define NBUCK 256   // dst buckets
#define TILE 4096   // edges per partition tile
#define EPT 16      // TILE / 256
#define MAXN 1024   // >= ceil(n_nodes / NBUCK)

__device__ __forceinline__ int bucket_of(int dstv, int n_nodes) {
  return (int)(((unsigned)dstv * 256u) / (unsigned)n_nodes);  // NBUCK=256
}

__global__ void k_bhist(const int* __restrict__ dst, int* __restrict__ btot,
                        int n_edges, int n_nodes) {
  __shared__ int h[NBUCK];
  int t = threadIdx.x;
  h[t] = 0;
  __syncthreads();
  int stride = gridDim.x * blockDim.x;
  for (int e = blockIdx.x * blockDim.x + t; e < n_edges; e += stride)
    atomicAdd(&h[bucket_of(dst[e], n_nodes)], 1);
  __syncthreads();
  if (h[t]) atomicAdd(&btot[t], h[t]);
}

__global__ void k_bscan(const int* __restrict__ btot, int* __restrict__ bbase,
                        int* __restrict__ gcur, int n_edges) {
  __shared__ int s[NBUCK];
  int t = threadIdx.x;
  s[t] = btot[t];
  __syncthreads();
  for (int off = 1; off < NBUCK; off <<= 1) {
    int add = (t >= off) ? s[t - off] : 0;
    __syncthreads();
    s[t] += add;
    __syncthreads();
  }
  int excl = (t == 0) ? 0 : s[t - 1];
  bbase[t] = excl;
  gcur[t] = excl;
  if (t == NBUCK - 1) bbase[NBUCK] = n_edges;
}

// LDS-tile multisplit: scatter packed (dloc<<18 | src) into bucket-contiguous regions
__global__ void k_part(const int* __restrict__ src, const int* __restrict__ dst,
                       int* __restrict__ gcur, unsigned* __restrict__ pairs,
                       int n_edges, int n_nodes, int chunk) {
  __shared__ int hist[NBUCK];
  __shared__ int base[NBUCK];
  int t = threadIdx.x;
  int beg = blockIdx.x * chunk;
  int end = min(beg + chunk, n_edges);
  for (int tbeg = beg; tbeg < end; tbeg += TILE) {
    int cnt = min(TILE, end - tbeg);
    hist[t] = 0;
    __syncthreads();
    unsigned pk[EPT];
    int r[EPT], bk[EPT];
    bool v[EPT];
#pragma unroll
    for (int k = 0; k < EPT; ++k) {
      int li = k * 256 + t;
      v[k] = li < cnt;
      if (v[k]) {
        int i = tbeg + li;
        int s = src[i];
        int d = dst[i];
        bk[k] = bucket_of(d, n_nodes);
        unsigned nb0 = ((unsigned)bk[k] * (unsigned)n_nodes + 255u) >> 8;
        pk[k] = (((unsigned)d - nb0) << 18) | (unsigned)s;
        r[k] = atomicAdd(&hist[bk[k]], 1);
      }
    }
    __syncthreads();
    base[t] = (hist[t] > 0) ? atomicAdd(&gcur[t], hist[t]) : 0;
    __syncthreads();
#pragma unroll
    for (int k = 0; k < EPT; ++k)
      if (v[k]) pairs[base[bk[k]] + r[k]] = pk[k];
    __syncthreads();
  }
}

// one block per bucket: LDS node-hist -> scan -> offs; scatter packed (x[src]<<18|src)
__global__ void k_bucket(const unsigned* __restrict__ pairs, const int* __restrict__ bbase,
                         const int* __restrict__ x, int* __restrict__ offs,
                         unsigned* __restrict__ idx, int n_nodes, int n_edges) {
  __shared__ int lcnt[MAXN];
  __shared__ int lcur[MAXN];
  __shared__ int stmp[256];
  int b = blockIdx.x, t = threadIdx.x;
  int nb0 = (int)((((unsigned)b * (unsigned)n_nodes) + 255u) >> 8);
  int nb1 = (int)((((unsigned)(b + 1) * (unsigned)n_nodes) + 255u) >> 8);
  if (nb1 > n_nodes) nb1 = n_nodes;
  int nn = nb1 - nb0;
  int ebeg = bbase[b], eend = bbase[b + 1];
  for (int i = t; i < nn; i += 256) lcnt[i] = 0;
  __syncthreads();
  for (int i = ebeg + t; i < eend; i += 256)
    atomicAdd(&lcnt[pairs[i] >> 18], 1);
  __syncthreads();
  int i0 = t * 4;
  int v0 = (i0 + 0 < nn) ? lcnt[i0 + 0] : 0;
  int v1 = (i0 + 1 < nn) ? lcnt[i0 + 1] : 0;
  int v2 = (i0 + 2 < nn) ? lcnt[i0 + 2] : 0;
  int v3 = (i0 + 3 < nn) ? lcnt[i0 + 3] : 0;
  stmp[t] = v0 + v1 + v2 + v3;
  __syncthreads();
  for (int off = 1; off < 256; off <<= 1) {
    int add = (t >= off) ? stmp[t - off] : 0;
    __syncthreads();
    stmp[t] += add;
    __syncthreads();
  }
  int run = ebeg + ((t == 0) ? 0 : stmp[t - 1]);
  if (i0 + 0 < nn) { lcur[i0 + 0] = run; offs[nb0 + i0 + 0] = run; run += v0; }
  if (i0 + 1 < nn) { lcur[i0 + 1] = run; offs[nb0 + i0 + 1] = run; run += v1; }
  if (i0 + 2 < nn) { lcur[i0 + 2] = run; offs[nb0 + i0 + 2] = run; run += v2; }
  if (i0 + 3 < nn) { lcur[i0 + 3] = run; offs[nb0 + i0 + 3] = run; run += v3; }
  if (b == NBUCK - 1 && t == 0) offs[n_nodes] = n_edges;
  __syncthreads();
  for (int i = ebeg + t; i < eend; i += 256) {
    unsigned e = pairs[i];
    int s = (int)(e & 0x3FFFFu);
    int pos = atomicAdd(&lcur[e >> 18], 1);
    idx[pos] = ((unsigned)x[s] << 18) | (unsigned)s;
  }
}

__global__ void k_transpose4(const float* __restrict__ a0, const float* __restrict__ a1,
                             const float* __restrict__ a2, const float* __restrict__ a3,
                             float* __restrict__ wt) {
  const float* s = (blockIdx.x == 0) ? a0 : (blockIdx.x == 1) ? a1 : (blockIdx.x == 2) ? a2 : a3;
  float* d = wt + blockIdx.x * 4096;
  for (int i = threadIdx.x; i < 4096; i += blockDim.x) {
    int r = i >> 6, c = i & 63;
    d[c * 64 + r] = s[i];
  }
}

// te = emb@W1l^T ; trb = emb@W1r^T + b1   (wave per vocab row)
__global__ void k_prep(const float* __restrict__ emb, const float* __restrict__ w1lT,
                       const float* __restrict__ w1rT, const float* __restrict__ b1,
                       float* __restrict__ te, float* __restrict__ trb, int vocab) {
  __shared__ float se[NPB][64];
  int wid = threadIdx.x >> 6, lane = threadIdx.x & 63;
  int v = blockIdx.x * NPB + wid;
  if (v >= vocab) return;
  se[wid][lane] = emb[(size_t)v * 64 + lane];
  __syncwarp();
  float aL = 0.f, aR = b1[lane];
#pragma unroll 8
  for (int f = 0; f < 64; ++f) {
    float ev = se[wid][f];
    aL = fmaf(ev, w1lT[f * 64 + lane], aL);
    aR = fmaf(ev, w1rT[f * 64 + lane], aR);
  }
  te[(size_t)v * 64 + lane] = aL;
  trb[(size_t)v * 64 + lane] = aR;
}

// conv1: per 64-edge chunk one coalesced idx load; 4 fp32 rows per gather via
// shfl-broadcast indices (independent loads). Epilogue: g1 (fp16), s1 (fp32).
__global__ void k_conv1(const unsigned* __restrict__ idx, const int* __restrict__ offs,
                        const float* __restrict__ te, const float* __restrict__ trb,
                        const int* __restrict__ x, const float* __restrict__ w2lT,
                        const float* __restrict__ w2rT, const float* __restrict__ b2,
                        __half* __restrict__ g1, float* __restrict__ s1, int n_nodes) {
  __shared__ float sm[NPB][64];
  int wid = threadIdx.x >> 6, lane = threadIdx.x & 63;
  int r = lane >> 4, s4 = (lane & 15) << 2;
  int node = blockIdx.x * NPB + wid;
  bool active = node < n_nodes;
  if (active) {
    int beg = offs[node], end = offs[node + 1];
    float4 acc = make_float4(0.f, 0.f, 0.f, 0.f);
    for (int c = beg; c < end; c += 64) {
      unsigned eidx = idx[min(c + lane, end - 1)];
      int nit = min(end - c, 64);
#pragma unroll 4
      for (int k = 0; k < nit; k += 4) {
        int kk = k + r;
        bool val = kk < nit;
        int sl = val ? kk : (nit - 1);
        int v = (int)(__shfl(eidx, sl) >> 18);
        const float4 t = *(const float4*)(te + ((size_t)v << 6) + s4);
        float m = val ? 1.f : 0.f;
        acc.x = fmaf(m, t.x, acc.x);
        acc.y = fmaf(m, t.y, acc.y);
        acc.z = fmaf(m, t.z, acc.z);
        acc.w = fmaf(m, t.w, acc.w);
      }
    }
    // reduce over 4 subrows (lane bits 4,5)
    acc.x += __shfl_xor(acc.x, 16); acc.y += __shfl_xor(acc.y, 16);
    acc.z += __shfl_xor(acc.z, 16); acc.w += __shfl_xor(acc.w, 16);
    acc.x += __shfl_xor(acc.x, 32); acc.y += __shfl_xor(acc.y, 32);
    acc.z += __shfl_xor(acc.z, 32); acc.w += __shfl_xor(acc.w, 32);
    int deg = end - beg;
    float inv = (deg > 0) ? 1.f / (float)deg : 0.f;
    if (lane < 16) {
      float4 t = *(const float4*)(trb + ((size_t)x[node] << 6) + s4);
      float4 h;
      h.x = fmaxf(fmaf(acc.x, inv, t.x), 0.f);
      h.y = fmaxf(fmaf(acc.y, inv, t.y), 0.f);
      h.z = fmaxf(fmaf(acc.z, inv, t.z), 0.f);
      h.w = fmaxf(fmaf(acc.w, inv, t.w), 0.f);
      *(float4*)&sm[wid][s4] = h;
    }
  }
  __syncthreads();
  if (active) {
    float aL = 0.f, aR = b2[lane];
    const float* hrow = sm[wid];
#pragma unroll 8
    for (int f = 0; f < 64; ++f) {
      float hv = hrow[f];
      aL = fmaf(hv, w2lT[f * 64 + lane], aL);
      aR = fmaf(hv, w2rT[f * 64 + lane], aR);
    }
    g1[((size_t)node << 6) + lane] = __float2half(aL);
    s1[((size_t)node << 6) + lane] = aR;
  }
}

// conv2: per 64-edge chunk one coalesced idx load; 8 fp16 rows per gather via
// shfl-broadcast indices. o[n] = relu(mean + s1) @ Wout^T.
__global__ void k_conv2(const unsigned* __restrict__ idx, const int* __restrict__ offs,
                        const __half* __restrict__ g1, const float* __restrict__ s1,
                        const float* __restrict__ wout, float* __restrict__ o,
                        int n_nodes) {
  __shared__ float sm[NPB][64];
  int wid = threadIdx.x >> 6, lane = threadIdx.x & 63;
  int r8 = lane >> 3, s8 = (lane & 7) << 3;
  int node = blockIdx.x * NPB + wid;
  bool active = node < n_nodes;
  if (active) {
    int beg = offs[node], end = offs[node + 1];
    float a[8];
#pragma unroll
    for (int c = 0; c < 8; ++c) a[c] = 0.f;
    for (int c = beg; c < end; c += 64) {
      unsigned eidx = idx[min(c + lane, end - 1)];
      int nit = min(end - c, 64);
#pragma unroll 4
      for (int k = 0; k < nit; k += 8) {
        int kk = k + r8;
        bool val = kk < nit;
        int sl = val ? kk : (nit - 1);
        int v = (int)(__shfl(eidx, sl) & 0x3FFFFu);
        uint4 u = *(const uint4*)(g1 + ((size_t)v << 6) + s8);
        float m = val ? 1.f : 0.f;
        const __half2* hp = (const __half2*)&u;
#pragma unroll
        for (int q = 0; q < 4; ++q) {
          float2 f = __half22float2(hp[q]);
          a[2 * q]     = fmaf(m, f.x, a[2 * q]);
          a[2 * q + 1] = fmaf(m, f.y, a[2 * q + 1]);
        }
      }
    }
#pragma unroll
    for (int c = 0; c < 8; ++c) {
      float v = a[c];
      v += __shfl_xor(v, 8);
      v += __shfl_xor(v, 16);
      v += __shfl_xor(v, 32);
      a[c] = v;
    }
    int deg = end - beg;
    float inv = (deg > 0) ? 1.f / (float)deg : 0.f;
    if (lane < 8) {
#pragma unroll
      for (int c = 0; c < 8; ++c) sm[wid][s8 + c] = a[c] * inv;
    }
  }
  __syncthreads();
  if (active) {
    float h2 = fmaxf(sm[wid][lane] + s1[((size_t)node << 6) + lane], 0.f);
    float p0 = h2 * wout[lane];
    float p1 = h2 * wout[64 + lane];
    for (int off = 32; off > 0; off >>= 1) {
      p0 += __shfl_down(p0, off);
      p1 += __shfl_down(p1, off);
    }
    if (lane == 0) {
      o[((size_t)node << 1) + 0] = p0;
      o[((size_t)node << 1) + 1] = p1;
    }
  }
}

__global__ void k_goffs(const int* __restrict__ batch, int* __restrict__ goffs,
                        int n_nodes, int n_graphs) {
  int i = blockIdx.x * blockDim.x + threadIdx.x;
  if (i >= n_nodes) return;
  int b = batch[i];
  int bp = (i == 0) ? -1 : batch[i - 1];
  for (int g = bp + 1; g <= b; ++g) goffs[g] = i;
  if (i == n_nodes - 1)
    for (int g = b + 1; g <= n_graphs; ++g) goffs[g] = n_nodes;
}

__global__ void k_pool(const float2* __restrict__ o, const int* __restrict__ goffs,
                       const float* __restrict__ bout, float* __restrict__ out,
                       int n_graphs) {
  int wid = threadIdx.x >> 6, lane = threadIdx.x & 63;
  int g = blockIdx.x * NPB + wid;
  if (g >= n_graphs) return;
  int beg = goffs[g], end = goffs[g + 1];
  float a0 = 0.f, a1 = 0.f;
  for (int n = beg + lane; n < end; n += 64) {
    float2 v = o[n];
    a0 += v.x;
    a1 += v.y;
  }
  for (int off = 32; off > 0; off >>= 1) {
    a0 += __shfl_down(a0, off);
    a1 += __shfl_down(a1, off);
  }
  if (lane == 0) {
    int cnt = end - beg;
    float inv = (cnt > 0) ? 1.f / (float)cnt : 0.f;
    out[g * 2 + 0] = a0 * inv + bout[0];
    out[g * 2 + 1] = a1 * inv + bout[1];
  }
}

extern "C" void kernel_launch(void* const* d_in, const int* in_sizes, int n_in,
                              void* d_out, int out_size, void* d_ws, size_t ws_size,
                              hipStream_t stream) {
  const int* x = (const int*)d_in[0];
  const int* ei = (const int*)d_in[1];
  const int* batch = (const int*)d_in[2];
  const float* emb = (const float*)d_in[3];
  const float* W1l = (const float*)d_in[4];
  const float* b1 = (const float*)d_in[5];
  const float* W1r = (const float*)d_in[6];
  const float* W2l = (const float*)d_in[7];
  const float* b2 = (const float*)d_in[8];
  const float* W2r = (const float*)d_in[9];
  const float* Wout = (const float*)d_in[10];
  const float* bout = (const float*)d_in[11];
  float* out = (float*)d_out;

  int n_nodes = in_sizes[0];
  int n_edges = in_sizes[1] / 2;
  int vocab = in_sizes[3] / 64;
  int n_graphs = out_size / 2;
  const int* src = ei;
  const int* dst = ei + n_edges;

  char* p = (char*)d_ws;
  auto alloc = [&](size_t bytes) -> void* {
    void* r = (void*)p;
    p += (bytes + 255) & ~(size_t)255;
    return r;
  };
  float* te = (float*)alloc((size_t)vocab * 64 * 4);
  float* trb = (float*)alloc((size_t)vocab * 64 * 4);
  float* wt = (float*)alloc(4 * 4096 * 4);
  int* offs = (int*)alloc((size_t)(n_nodes + 1) * 4);
  int* goffs = (int*)alloc((size_t)(n_graphs + 1) * 4);
  int* btot = (int*)alloc(NBUCK * 4);
  int* bbase = (int*)alloc((NBUCK + 1) * 4);
  int* gcur = (int*)alloc(NBUCK * 4);
  unsigned* idx = (unsigned*)alloc((size_t)n_edges * 4);   // packed (x[src]<<18)|src
  unsigned* pairs = (unsigned*)alloc((size_t)n_edges * 4); // reused as g1 after k_bucket
  float* s1 = (float*)alloc((size_t)n_nodes * 64 * 4);
  float* o = (float*)alloc((size_t)n_nodes * 2 * 4);
  __half* g1 = (__half*)pairs;  // pairs dead before k_conv1 writes g1

  hipMemsetAsync(btot, 0, NBUCK * 4, stream);

  k_transpose4<<<4, 256, 0, stream>>>(W1l, W1r, W2l, W2r, wt);
  k_prep<<<(vocab + NPB - 1) / NPB, 64 * NPB, 0, stream>>>(emb, wt, wt + 4096, b1, te, trb, vocab);

  k_bhist<<<1024, 256, 0, stream>>>(dst, btot, n_edges, n_nodes);
  k_bscan<<<1, NBUCK, 0, stream>>>(btot, bbase, gcur, n_edges);
  int part_blocks = 512;
  int chunk = (n_edges + part_blocks - 1) / part_blocks;
  k_part<<<part_blocks, 256, 0, stream>>>(src, dst, gcur, pairs, n_edges, n_nodes, chunk);
  k_bucket<<<NBUCK, 256, 0, stream>>>(pairs, bbase, x, offs, idx, n_nodes, n_edges);

  k_goffs<<<(n_nodes + 255) / 256, 256, 0, stream>>>(batch, goffs, n_nodes, n_graphs);

  k_conv1<<<(n_nodes + NPB - 1) / NPB, 64 * NPB, 0, stream>>>(idx, offs, te, trb, x, wt + 8192, wt + 12288, b2, g1, s1, n_nodes);
  k_conv2<<<(n_nodes + NPB - 1) / NPB, 64 * NPB, 0, stream>>>(idx, offs, g1, s1, Wout, o, n_nodes);
  k_pool<<<(n_graphs + NPB - 1) / NPB, 64 * NPB, 0, stream>>>((const float2*)o, goffs, bout, out, n_graphs);
}

// Round 6
// 568.740 us; speedup vs baseline: 2.7753x; 1.0495x over previous
//
#include <hip/hip_runtime.h>
#include <hip/hip_fp16.h>
#include <stdint.h>

// GNN: 2x SAGEConv(mean)+ReLU + mean-pool + linear, algebraically refactored:
//  te = emb@W1l^T (fp16, L2-resident gather table), trb = emb@W1r^T + b1 (fp32)
//  conv1: h1 = relu(mean(te[x[src]]) + trb[x[n]]); g1 = h1@W2l^T (fp16); s1 = h1@W2r^T + b2
//  conv2: h2 = relu(mean(g1[src]) + s1[n]); o[n] = h2@Wout^T
//  pool:  out[g] = mean(o) + bout
// idx[pos] = (x[src]<<18) | src  (vocab<2^14, n_nodes<2^18).
// Gather: fp16 rows = 128B = 8 lanes x 16B -> 8 edges per wave-load; manual 4x
// unroll with named uint4 loads keeps 4 loads in flight (VGPR~45, not 20).

#define NPB 4       // waves per block in conv/pool kernels
#define NBUCK 256   // dst buckets
#define TILE 4096   // edges per partition tile
#define EPT 16      // TILE / 256
#define MAXN 1024   // >= ceil(n_nodes / NBUCK)

__device__ __forceinline__ int bucket_of(int dstv, int n_nodes) {
  return (int)(((unsigned)dstv * 256u) / (unsigned)n_nodes);  // NBUCK=256
}

__device__ __forceinline__ void acc8h(float* a, uint4 u, float m) {
  const __half2* hp = (const __half2*)&u;
#pragma unroll
  for (int q = 0; q < 4; ++q) {
    float2 f = __half22float2(hp[q]);
    a[2 * q]     = fmaf(m, f.x, a[2 * q]);
    a[2 * q + 1] = fmaf(m, f.y, a[2 * q + 1]);
  }
}

__global__ void k_bhist(const int* __restrict__ dst, int* __restrict__ btot,
                        int n_edges, int n_nodes) {
  __shared__ int h[NBUCK];
  int t = threadIdx.x;
  h[t] = 0;
  __syncthreads();
  int stride = gridDim.x * blockDim.x;
  for (int e = blockIdx.x * blockDim.x + t; e < n_edges; e += stride)
    atomicAdd(&h[bucket_of(dst[e], n_nodes)], 1);
  __syncthreads();
  if (h[t]) atomicAdd(&btot[t], h[t]);
}

__global__ void k_bscan(const int* __restrict__ btot, int* __restrict__ bbase,
                        int* __restrict__ gcur, int n_edges) {
  __shared__ int s[NBUCK];
  int t = threadIdx.x;
  s[t] = btot[t];
  __syncthreads();
  for (int off = 1; off < NBUCK; off <<= 1) {
    int add = (t >= off) ? s[t - off] : 0;
    __syncthreads();
    s[t] += add;
    __syncthreads();
  }
  int excl = (t == 0) ? 0 : s[t - 1];
  bbase[t] = excl;
  gcur[t] = excl;
  if (t == NBUCK - 1) bbase[NBUCK] = n_edges;
}

// LDS-tile multisplit: scatter packed (dloc<<18 | src) into bucket-contiguous regions
__global__ void k_part(const int* __restrict__ src, const int* __restrict__ dst,
                       int* __restrict__ gcur, unsigned* __restrict__ pairs,
                       int n_edges, int n_nodes, int chunk) {
  __shared__ int hist[NBUCK];
  __shared__ int base[NBUCK];
  int t = threadIdx.x;
  int beg = blockIdx.x * chunk;
  int end = min(beg + chunk, n_edges);
  for (int tbeg = beg; tbeg < end; tbeg += TILE) {
    int cnt = min(TILE, end - tbeg);
    hist[t] = 0;
    __syncthreads();
    unsigned pk[EPT];
    int r[EPT], bk[EPT];
    bool v[EPT];
#pragma unroll
    for (int k = 0; k < EPT; ++k) {
      int li = k * 256 + t;
      v[k] = li < cnt;
      if (v[k]) {
        int i = tbeg + li;
        int s = src[i];
        int d = dst[i];
        bk[k] = bucket_of(d, n_nodes);
        unsigned nb0 = ((unsigned)bk[k] * (unsigned)n_nodes + 255u) >> 8;
        pk[k] = (((unsigned)d - nb0) << 18) | (unsigned)s;
        r[k] = atomicAdd(&hist[bk[k]], 1);
      }
    }
    __syncthreads();
    base[t] = (hist[t] > 0) ? atomicAdd(&gcur[t], hist[t]) : 0;
    __syncthreads();
#pragma unroll
    for (int k = 0; k < EPT; ++k)
      if (v[k]) pairs[base[bk[k]] + r[k]] = pk[k];
    __syncthreads();
  }
}

// one block per bucket: LDS node-hist -> scan -> offs; scatter packed (x[src]<<18|src)
__global__ void k_bucket(const unsigned* __restrict__ pairs, const int* __restrict__ bbase,
                         const int* __restrict__ x, int* __restrict__ offs,
                         unsigned* __restrict__ idx, int n_nodes, int n_edges) {
  __shared__ int lcnt[MAXN];
  __shared__ int lcur[MAXN];
  __shared__ int stmp[256];
  int b = blockIdx.x, t = threadIdx.x;
  int nb0 = (int)((((unsigned)b * (unsigned)n_nodes) + 255u) >> 8);
  int nb1 = (int)((((unsigned)(b + 1) * (unsigned)n_nodes) + 255u) >> 8);
  if (nb1 > n_nodes) nb1 = n_nodes;
  int nn = nb1 - nb0;
  int ebeg = bbase[b], eend = bbase[b + 1];
  for (int i = t; i < nn; i += 256) lcnt[i] = 0;
  __syncthreads();
  for (int i = ebeg + t; i < eend; i += 256)
    atomicAdd(&lcnt[pairs[i] >> 18], 1);
  __syncthreads();
  int i0 = t * 4;
  int v0 = (i0 + 0 < nn) ? lcnt[i0 + 0] : 0;
  int v1 = (i0 + 1 < nn) ? lcnt[i0 + 1] : 0;
  int v2 = (i0 + 2 < nn) ? lcnt[i0 + 2] : 0;
  int v3 = (i0 + 3 < nn) ? lcnt[i0 + 3] : 0;
  stmp[t] = v0 + v1 + v2 + v3;
  __syncthreads();
  for (int off = 1; off < 256; off <<= 1) {
    int add = (t >= off) ? stmp[t - off] : 0;
    __syncthreads();
    stmp[t] += add;
    __syncthreads();
  }
  int run = ebeg + ((t == 0) ? 0 : stmp[t - 1]);
  if (i0 + 0 < nn) { lcur[i0 + 0] = run; offs[nb0 + i0 + 0] = run; run += v0; }
  if (i0 + 1 < nn) { lcur[i0 + 1] = run; offs[nb0 + i0 + 1] = run; run += v1; }
  if (i0 + 2 < nn) { lcur[i0 + 2] = run; offs[nb0 + i0 + 2] = run; run += v2; }
  if (i0 + 3 < nn) { lcur[i0 + 3] = run; offs[nb0 + i0 + 3] = run; run += v3; }
  if (b == NBUCK - 1 && t == 0) offs[n_nodes] = n_edges;
  __syncthreads();
  for (int i = ebeg + t; i < eend; i += 256) {
    unsigned e = pairs[i];
    int s = (int)(e & 0x3FFFFu);
    int pos = atomicAdd(&lcur[e >> 18], 1);
    idx[pos] = ((unsigned)x[s] << 18) | (unsigned)s;
  }
}

__global__ void k_transpose4(const float* __restrict__ a0, const float* __restrict__ a1,
                             const float* __restrict__ a2, const float* __restrict__ a3,
                             float* __restrict__ wt) {
  const float* s = (blockIdx.x == 0) ? a0 : (blockIdx.x == 1) ? a1 : (blockIdx.x == 2) ? a2 : a3;
  float* d = wt + blockIdx.x * 4096;
  for (int i = threadIdx.x; i < 4096; i += blockDim.x) {
    int r = i >> 6, c = i & 63;
    d[c * 64 + r] = s[i];
  }
}

// te = emb@W1l^T (fp16) ; trb = emb@W1r^T + b1 (fp32)   (wave per vocab row)
__global__ void k_prep(const float* __restrict__ emb, const float* __restrict__ w1lT,
                       const float* __restrict__ w1rT, const float* __restrict__ b1,
                       __half* __restrict__ te, float* __restrict__ trb, int vocab) {
  __shared__ float se[NPB][64];
  int wid = threadIdx.x >> 6, lane = threadIdx.x & 63;
  int v = blockIdx.x * NPB + wid;
  if (v >= vocab) return;
  se[wid][lane] = emb[(size_t)v * 64 + lane];
  __syncwarp();
  float aL = 0.f, aR = b1[lane];
#pragma unroll 8
  for (int f = 0; f < 64; ++f) {
    float ev = se[wid][f];
    aL = fmaf(ev, w1lT[f * 64 + lane], aL);
    aR = fmaf(ev, w1rT[f * 64 + lane], aR);
  }
  te[(size_t)v * 64 + lane] = __float2half(aL);
  trb[(size_t)v * 64 + lane] = aR;
}

// conv1: per 64-edge chunk one coalesced idx load; 8 fp16 rows per gather via
// shfl-broadcast indices; manual 4x unroll -> 4 independent uint4 loads in flight.
__global__ void k_conv1(const unsigned* __restrict__ idx, const int* __restrict__ offs,
                        const __half* __restrict__ te, const float* __restrict__ trb,
                        const int* __restrict__ x, const float* __restrict__ w2lT,
                        const float* __restrict__ w2rT, const float* __restrict__ b2,
                        __half* __restrict__ g1, float* __restrict__ s1, int n_nodes) {
  __shared__ float sm[NPB][64];
  int wid = threadIdx.x >> 6, lane = threadIdx.x & 63;
  int r8 = lane >> 3, s8 = (lane & 7) << 3;
  int node = blockIdx.x * NPB + wid;
  bool active = node < n_nodes;
  if (active) {
    int beg = offs[node], end = offs[node + 1];
    float a[8];
#pragma unroll
    for (int q = 0; q < 8; ++q) a[q] = 0.f;
    for (int c = beg; c < end; c += 64) {
      unsigned eidx = idx[min(c + lane, end - 1)];
      int nit = min(end - c, 64);
      for (int k = 0; k < nit; k += 32) {
        int k0 = k + r8, k1 = k0 + 8, k2 = k0 + 16, k3 = k0 + 24;
        int v0 = (int)(__shfl(eidx, min(k0, nit - 1)) >> 18);
        int v1 = (int)(__shfl(eidx, min(k1, nit - 1)) >> 18);
        int v2 = (int)(__shfl(eidx, min(k2, nit - 1)) >> 18);
        int v3 = (int)(__shfl(eidx, min(k3, nit - 1)) >> 18);
        uint4 u0 = *(const uint4*)(te + ((size_t)v0 << 6) + s8);
        uint4 u1 = *(const uint4*)(te + ((size_t)v1 << 6) + s8);
        uint4 u2 = *(const uint4*)(te + ((size_t)v2 << 6) + s8);
        uint4 u3 = *(const uint4*)(te + ((size_t)v3 << 6) + s8);
        acc8h(a, u0, (k0 < nit) ? 1.f : 0.f);
        acc8h(a, u1, (k1 < nit) ? 1.f : 0.f);
        acc8h(a, u2, (k2 < nit) ? 1.f : 0.f);
        acc8h(a, u3, (k3 < nit) ? 1.f : 0.f);
      }
    }
#pragma unroll
    for (int q = 0; q < 8; ++q) {
      a[q] += __shfl_xor(a[q], 8);
      a[q] += __shfl_xor(a[q], 16);
      a[q] += __shfl_xor(a[q], 32);
    }
    int deg = end - beg;
    float inv = (deg > 0) ? 1.f / (float)deg : 0.f;
    if (lane < 8) {
      int xv = x[node];
      const float* tp = trb + ((size_t)xv << 6) + s8;
      float4 t0 = *(const float4*)tp;
      float4 t1 = *(const float4*)(tp + 4);
      float4 h0, h1;
      h0.x = fmaxf(fmaf(a[0], inv, t0.x), 0.f);
      h0.y = fmaxf(fmaf(a[1], inv, t0.y), 0.f);
      h0.z = fmaxf(fmaf(a[2], inv, t0.z), 0.f);
      h0.w = fmaxf(fmaf(a[3], inv, t0.w), 0.f);
      h1.x = fmaxf(fmaf(a[4], inv, t1.x), 0.f);
      h1.y = fmaxf(fmaf(a[5], inv, t1.y), 0.f);
      h1.z = fmaxf(fmaf(a[6], inv, t1.z), 0.f);
      h1.w = fmaxf(fmaf(a[7], inv, t1.w), 0.f);
      *(float4*)&sm[wid][s8] = h0;
      *(float4*)&sm[wid][s8 + 4] = h1;
    }
  }
  __syncthreads();
  if (active) {
    float aL = 0.f, aR = b2[lane];
    const float* hrow = sm[wid];
#pragma unroll
    for (int q = 0; q < 16; ++q) {
      float4 hv = *(const float4*)&hrow[q * 4];
      int f = q * 4;
      aL = fmaf(hv.x, w2lT[(f + 0) * 64 + lane], aL);
      aR = fmaf(hv.x, w2rT[(f + 0) * 64 + lane], aR);
      aL = fmaf(hv.y, w2lT[(f + 1) * 64 + lane], aL);
      aR = fmaf(hv.y, w2rT[(f + 1) * 64 + lane], aR);
      aL = fmaf(hv.z, w2lT[(f + 2) * 64 + lane], aL);
      aR = fmaf(hv.z, w2rT[(f + 2) * 64 + lane], aR);
      aL = fmaf(hv.w, w2lT[(f + 3) * 64 + lane], aL);
      aR = fmaf(hv.w, w2rT[(f + 3) * 64 + lane], aR);
    }
    g1[((size_t)node << 6) + lane] = __float2half(aL);
    s1[((size_t)node << 6) + lane] = aR;
  }
}

// conv2: same gather structure on g1 (fp16); o[n] = relu(mean + s1) @ Wout^T.
__global__ void k_conv2(const unsigned* __restrict__ idx, const int* __restrict__ offs,
                        const __half* __restrict__ g1, const float* __restrict__ s1,
                        const float* __restrict__ wout, float* __restrict__ o,
                        int n_nodes) {
  __shared__ float sm[NPB][64];
  int wid = threadIdx.x >> 6, lane = threadIdx.x & 63;
  int r8 = lane >> 3, s8 = (lane & 7) << 3;
  int node = blockIdx.x * NPB + wid;
  bool active = node < n_nodes;
  if (active) {
    int beg = offs[node], end = offs[node + 1];
    float a[8];
#pragma unroll
    for (int q = 0; q < 8; ++q) a[q] = 0.f;
    for (int c = beg; c < end; c += 64) {
      unsigned eidx = idx[min(c + lane, end - 1)];
      int nit = min(end - c, 64);
      for (int k = 0; k < nit; k += 32) {
        int k0 = k + r8, k1 = k0 + 8, k2 = k0 + 16, k3 = k0 + 24;
        int v0 = (int)(__shfl(eidx, min(k0, nit - 1)) & 0x3FFFFu);
        int v1 = (int)(__shfl(eidx, min(k1, nit - 1)) & 0x3FFFFu);
        int v2 = (int)(__shfl(eidx, min(k2, nit - 1)) & 0x3FFFFu);
        int v3 = (int)(__shfl(eidx, min(k3, nit - 1)) & 0x3FFFFu);
        uint4 u0 = *(const uint4*)(g1 + ((size_t)v0 << 6) + s8);
        uint4 u1 = *(const uint4*)(g1 + ((size_t)v1 << 6) + s8);
        uint4 u2 = *(const uint4*)(g1 + ((size_t)v2 << 6) + s8);
        uint4 u3 = *(const uint4*)(g1 + ((size_t)v3 << 6) + s8);
        acc8h(a, u0, (k0 < nit) ? 1.f : 0.f);
        acc8h(a, u1, (k1 < nit) ? 1.f : 0.f);
        acc8h(a, u2, (k2 < nit) ? 1.f : 0.f);
        acc8h(a, u3, (k3 < nit) ? 1.f : 0.f);
      }
    }
#pragma unroll
    for (int q = 0; q < 8; ++q) {
      a[q] += __shfl_xor(a[q], 8);
      a[q] += __shfl_xor(a[q], 16);
      a[q] += __shfl_xor(a[q], 32);
    }
    int deg = end - beg;
    float inv = (deg > 0) ? 1.f / (float)deg : 0.f;
    if (lane < 8) {
#pragma unroll
      for (int q = 0; q < 8; ++q) sm[wid][s8 + q] = a[q] * inv;
    }
  }
  __syncthreads();
  if (active) {
    float h2 = fmaxf(sm[wid][lane] + s1[((size_t)node << 6) + lane], 0.f);
    float p0 = h2 * wout[lane];
    float p1 = h2 * wout[64 + lane];
    for (int off = 32; off > 0; off >>= 1) {
      p0 += __shfl_down(p0, off);
      p1 += __shfl_down(p1, off);
    }
    if (lane == 0) {
      o[((size_t)node << 1) + 0] = p0;
      o[((size_t)node << 1) + 1] = p1;
    }
  }
}

__global__ void k_goffs(const int* __restrict__ batch, int* __restrict__ goffs,
                        int n_nodes, int n_graphs) {
  int i = blockIdx.x * blockDim.x + threadIdx.x;
  if (i >= n_nodes) return;
  int b = batch[i];
  int bp = (i == 0) ? -1 : batch[i - 1];
  for (int g = bp + 1; g <= b; ++g) goffs[g] = i;
  if (i == n_nodes - 1)
    for (int g = b + 1; g <= n_graphs; ++g) goffs[g] = n_nodes;
}

__global__ void k_pool(const float2* __restrict__ o, const int* __restrict__ goffs,
                       const float* __restrict__ bout, float* __restrict__ out,
                       int n_graphs) {
  int wid = threadIdx.x >> 6, lane = threadIdx.x & 63;
  int g = blockIdx.x * NPB + wid;
  if (g >= n_graphs) return;
  int beg = goffs[g], end = goffs[g + 1];
  float a0 = 0.f, a1 = 0.f;
  for (int n = beg + lane; n < end; n += 64) {
    float2 v = o[n];
    a0 += v.x;
    a1 += v.y;
  }
  for (int off = 32; off > 0; off >>= 1) {
    a0 += __shfl_down(a0, off);
    a1 += __shfl_down(a1, off);
  }
  if (lane == 0) {
    int cnt = end - beg;
    float inv = (cnt > 0) ? 1.f / (float)cnt : 0.f;
    out[g * 2 + 0] = a0 * inv + bout[0];
    out[g * 2 + 1] = a1 * inv + bout[1];
  }
}

extern "C" void kernel_launch(void* const* d_in, const int* in_sizes, int n_in,
                              void* d_out, int out_size, void* d_ws, size_t ws_size,
                              hipStream_t stream) {
  const int* x = (const int*)d_in[0];
  const int* ei = (const int*)d_in[1];
  const int* batch = (const int*)d_in[2];
  const float* emb = (const float*)d_in[3];
  const float* W1l = (const float*)d_in[4];
  const float* b1 = (const float*)d_in[5];
  const float* W1r = (const float*)d_in[6];
  const float* W2l = (const float*)d_in[7];
  const float* b2 = (const float*)d_in[8];
  const float* W2r = (const float*)d_in[9];
  const float* Wout = (const float*)d_in[10];
  const float* bout = (const float*)d_in[11];
  float* out = (float*)d_out;

  int n_nodes = in_sizes[0];
  int n_edges = in_sizes[1] / 2;
  int vocab = in_sizes[3] / 64;
  int n_graphs = out_size / 2;
  const int* src = ei;
  const int* dst = ei + n_edges;

  char* p = (char*)d_ws;
  auto alloc = [&](size_t bytes) -> void* {
    void* r = (void*)p;
    p += (bytes + 255) & ~(size_t)255;
    return r;
  };
  __half* te = (__half*)alloc((size_t)vocab * 64 * 2);
  float* trb = (float*)alloc((size_t)vocab * 64 * 4);
  float* wt = (float*)alloc(4 * 4096 * 4);
  int* offs = (int*)alloc((size_t)(n_nodes + 1) * 4);
  int* goffs = (int*)alloc((size_t)(n_graphs + 1) * 4);
  int* btot = (int*)alloc(NBUCK * 4);
  int* bbase = (int*)alloc((NBUCK + 1) * 4);
  int* gcur = (int*)alloc(NBUCK * 4);
  unsigned* idx = (unsigned*)alloc((size_t)n_edges * 4);   // packed (x[src]<<18)|src
  unsigned* pairs = (unsigned*)alloc((size_t)n_edges * 4); // reused as g1 after k_bucket
  float* s1 = (float*)alloc((size_t)n_nodes * 64 * 4);
  float* o = (float*)alloc((size_t)n_nodes * 2 * 4);
  __half* g1 = (__half*)pairs;  // pairs dead before k_conv1 writes g1

  hipMemsetAsync(btot, 0, NBUCK * 4, stream);

  k_transpose4<<<4, 256, 0, stream>>>(W1l, W1r, W2l, W2r, wt);
  k_prep<<<(vocab + NPB - 1) / NPB, 64 * NPB, 0, stream>>>(emb, wt, wt + 4096, b1, te, trb, vocab);

  k_bhist<<<1024, 256, 0, stream>>>(dst, btot, n_edges, n_nodes);
  k_bscan<<<1, NBUCK, 0, stream>>>(btot, bbase, gcur, n_edges);
  int part_blocks = 512;
  int chunk = (n_edges + part_blocks - 1) / part_blocks;
  k_part<<<part_blocks, 256, 0, stream>>>(src, dst, gcur, pairs, n_edges, n_nodes, chunk);
  k_bucket<<<NBUCK, 256, 0, stream>>>(pairs, bbase, x, offs, idx, n_nodes, n_edges);

  k_goffs<<<(n_nodes + 255) / 256, 256, 0, stream>>>(batch, goffs, n_nodes, n_graphs);

  k_conv1<<<(n_nodes + NPB - 1) / NPB, 64 * NPB, 0, stream>>>(idx, offs, te, trb, x, wt + 8192, wt + 12288, b2, g1, s1, n_nodes);
  k_conv2<<<(n_nodes + NPB - 1) / NPB, 64 * NPB, 0, stream>>>(idx, offs, g1, s1, Wout, o, n_nodes);
  k_pool<<<(n_graphs + NPB - 1) / NPB, 64 * NPB, 0, stream>>>((const float2*)o, goffs, bout, out, n_graphs);
}

// Round 7
// 475.339 us; speedup vs baseline: 3.3206x; 1.1965x over previous
//
#include <hip/hip_runtime.h>
#include <hip/hip_fp16.h>
#include <stdint.h>

// GNN: 2x SAGEConv(mean)+ReLU + mean-pool + linear, algebraically refactored:
//  te = emb@W1l^T (fp16, L2-resident gather table), trb = emb@W1r^T + b1 (fp32)
//  conv1: h1 = relu(mean(te[x[src]]) + trb[x[n]]); g1 = h1@W2l^T (fp16); s1 = h1@W2r^T + b2
//  conv2: h2 = relu(mean(g1[src]) + s1[n]); o[n] = h2@Wout^T
//  pool:  out[g] = mean(o) + bout
// idx[pos] = (x[src]<<18) | src  (vocab<2^14, n_nodes<2^18).
// conv1: each wave gathers NPW=4 nodes (h-rows in wave-private LDS), then ONE
// batched epilogue: per f, 2 weight loads serve 8 fma (4 nodes x 2 matvecs).

#define NPB 4       // waves per block
#define NPW 4       // nodes per wave in conv1 (epilogue amortization)
#define NBUCK 256   // dst buckets
#define TILE 4096   // edges per partition tile
#define EPT 16      // TILE / 256
#define MAXN 1024   // >= ceil(n_nodes / NBUCK)

__device__ __forceinline__ int bucket_of(int dstv, int n_nodes) {
  return (int)(((unsigned)dstv * 256u) / (unsigned)n_nodes);  // NBUCK=256
}

__device__ __forceinline__ void acc8h(float* a, uint4 u, float m) {
  const __half2* hp = (const __half2*)&u;
#pragma unroll
  for (int q = 0; q < 4; ++q) {
    float2 f = __half22float2(hp[q]);
    a[2 * q]     = fmaf(m, f.x, a[2 * q]);
    a[2 * q + 1] = fmaf(m, f.y, a[2 * q + 1]);
  }
}

__global__ void k_bhist(const int* __restrict__ dst, int* __restrict__ btot,
                        int n_edges, int n_nodes) {
  __shared__ int h[NBUCK];
  int t = threadIdx.x;
  h[t] = 0;
  __syncthreads();
  int stride = gridDim.x * blockDim.x;
  for (int e = blockIdx.x * blockDim.x + t; e < n_edges; e += stride)
    atomicAdd(&h[bucket_of(dst[e], n_nodes)], 1);
  __syncthreads();
  if (h[t]) atomicAdd(&btot[t], h[t]);
}

__global__ void k_bscan(const int* __restrict__ btot, int* __restrict__ bbase,
                        int* __restrict__ gcur, int n_edges) {
  __shared__ int s[NBUCK];
  int t = threadIdx.x;
  s[t] = btot[t];
  __syncthreads();
  for (int off = 1; off < NBUCK; off <<= 1) {
    int add = (t >= off) ? s[t - off] : 0;
    __syncthreads();
    s[t] += add;
    __syncthreads();
  }
  int excl = (t == 0) ? 0 : s[t - 1];
  bbase[t] = excl;
  gcur[t] = excl;
  if (t == NBUCK - 1) bbase[NBUCK] = n_edges;
}

// LDS-tile multisplit: scatter packed (dloc<<18 | src) into bucket-contiguous regions
__global__ void k_part(const int* __restrict__ src, const int* __restrict__ dst,
                       int* __restrict__ gcur, unsigned* __restrict__ pairs,
                       int n_edges, int n_nodes, int chunk) {
  __shared__ int hist[NBUCK];
  __shared__ int base[NBUCK];
  int t = threadIdx.x;
  int beg = blockIdx.x * chunk;
  int end = min(beg + chunk, n_edges);
  for (int tbeg = beg; tbeg < end; tbeg += TILE) {
    int cnt = min(TILE, end - tbeg);
    hist[t] = 0;
    __syncthreads();
    unsigned pk[EPT];
    int r[EPT], bk[EPT];
    bool v[EPT];
#pragma unroll
    for (int k = 0; k < EPT; ++k) {
      int li = k * 256 + t;
      v[k] = li < cnt;
      if (v[k]) {
        int i = tbeg + li;
        int s = src[i];
        int d = dst[i];
        bk[k] = bucket_of(d, n_nodes);
        unsigned nb0 = ((unsigned)bk[k] * (unsigned)n_nodes + 255u) >> 8;
        pk[k] = (((unsigned)d - nb0) << 18) | (unsigned)s;
        r[k] = atomicAdd(&hist[bk[k]], 1);
      }
    }
    __syncthreads();
    base[t] = (hist[t] > 0) ? atomicAdd(&gcur[t], hist[t]) : 0;
    __syncthreads();
#pragma unroll
    for (int k = 0; k < EPT; ++k)
      if (v[k]) pairs[base[bk[k]] + r[k]] = pk[k];
    __syncthreads();
  }
}

// one block per bucket: LDS node-hist -> scan -> offs; scatter packed (x[src]<<18|src)
__global__ void k_bucket(const unsigned* __restrict__ pairs, const int* __restrict__ bbase,
                         const int* __restrict__ x, int* __restrict__ offs,
                         unsigned* __restrict__ idx, int n_nodes, int n_edges) {
  __shared__ int lcnt[MAXN];
  __shared__ int lcur[MAXN];
  __shared__ int stmp[256];
  int b = blockIdx.x, t = threadIdx.x;
  int nb0 = (int)((((unsigned)b * (unsigned)n_nodes) + 255u) >> 8);
  int nb1 = (int)((((unsigned)(b + 1) * (unsigned)n_nodes) + 255u) >> 8);
  if (nb1 > n_nodes) nb1 = n_nodes;
  int nn = nb1 - nb0;
  int ebeg = bbase[b], eend = bbase[b + 1];
  for (int i = t; i < nn; i += 256) lcnt[i] = 0;
  __syncthreads();
  for (int i = ebeg + t; i < eend; i += 256)
    atomicAdd(&lcnt[pairs[i] >> 18], 1);
  __syncthreads();
  int i0 = t * 4;
  int v0 = (i0 + 0 < nn) ? lcnt[i0 + 0] : 0;
  int v1 = (i0 + 1 < nn) ? lcnt[i0 + 1] : 0;
  int v2 = (i0 + 2 < nn) ? lcnt[i0 + 2] : 0;
  int v3 = (i0 + 3 < nn) ? lcnt[i0 + 3] : 0;
  stmp[t] = v0 + v1 + v2 + v3;
  __syncthreads();
  for (int off = 1; off < 256; off <<= 1) {
    int add = (t >= off) ? stmp[t - off] : 0;
    __syncthreads();
    stmp[t] += add;
    __syncthreads();
  }
  int run = ebeg + ((t == 0) ? 0 : stmp[t - 1]);
  if (i0 + 0 < nn) { lcur[i0 + 0] = run; offs[nb0 + i0 + 0] = run; run += v0; }
  if (i0 + 1 < nn) { lcur[i0 + 1] = run; offs[nb0 + i0 + 1] = run; run += v1; }
  if (i0 + 2 < nn) { lcur[i0 + 2] = run; offs[nb0 + i0 + 2] = run; run += v2; }
  if (i0 + 3 < nn) { lcur[i0 + 3] = run; offs[nb0 + i0 + 3] = run; run += v3; }
  if (b == NBUCK - 1 && t == 0) offs[n_nodes] = n_edges;
  __syncthreads();
  for (int i = ebeg + t; i < eend; i += 256) {
    unsigned e = pairs[i];
    int s = (int)(e & 0x3FFFFu);
    int pos = atomicAdd(&lcur[e >> 18], 1);
    idx[pos] = ((unsigned)x[s] << 18) | (unsigned)s;
  }
}

__global__ void k_transpose4(const float* __restrict__ a0, const float* __restrict__ a1,
                             const float* __restrict__ a2, const float* __restrict__ a3,
                             float* __restrict__ wt) {
  const float* s = (blockIdx.x == 0) ? a0 : (blockIdx.x == 1) ? a1 : (blockIdx.x == 2) ? a2 : a3;
  float* d = wt + blockIdx.x * 4096;
  for (int i = threadIdx.x; i < 4096; i += blockDim.x) {
    int r = i >> 6, c = i & 63;
    d[c * 64 + r] = s[i];
  }
}

// te = emb@W1l^T (fp16) ; trb = emb@W1r^T + b1 (fp32)   (wave per vocab row)
__global__ void k_prep(const float* __restrict__ emb, const float* __restrict__ w1lT,
                       const float* __restrict__ w1rT, const float* __restrict__ b1,
                       __half* __restrict__ te, float* __restrict__ trb, int vocab) {
  __shared__ float se[NPB][64];
  int wid = threadIdx.x >> 6, lane = threadIdx.x & 63;
  int v = blockIdx.x * NPB + wid;
  if (v >= vocab) return;
  se[wid][lane] = emb[(size_t)v * 64 + lane];
  __syncwarp();
  float aL = 0.f, aR = b1[lane];
#pragma unroll 8
  for (int f = 0; f < 64; ++f) {
    float ev = se[wid][f];
    aL = fmaf(ev, w1lT[f * 64 + lane], aL);
    aR = fmaf(ev, w1rT[f * 64 + lane], aR);
  }
  te[(size_t)v * 64 + lane] = __float2half(aL);
  trb[(size_t)v * 64 + lane] = aR;
}

// conv1: each wave gathers NPW nodes into wave-private LDS rows, then one
// batched epilogue (per f: 2 weight loads + 4 LDS broadcasts + 8 fma).
__global__ void k_conv1(const unsigned* __restrict__ idx, const int* __restrict__ offs,
                        const __half* __restrict__ te, const float* __restrict__ trb,
                        const int* __restrict__ x, const float* __restrict__ w2lT,
                        const float* __restrict__ w2rT, const float* __restrict__ b2,
                        __half* __restrict__ g1, float* __restrict__ s1, int n_nodes) {
  __shared__ float sm[NPB * NPW][64];
  int wid = threadIdx.x >> 6, lane = threadIdx.x & 63;
  int r8 = lane >> 3, s8 = (lane & 7) << 3;
  int nbase = (blockIdx.x * NPB + wid) * NPW;
  if (nbase >= n_nodes) return;
  int nvalid = min(NPW, n_nodes - nbase);

  // ---- phase 1: gather NPW nodes (wave-private LDS rows, no barrier) ----
  for (int i = 0; i < nvalid; ++i) {
    int node = nbase + i;
    int beg = offs[node], end = offs[node + 1];
    float a[8];
#pragma unroll
    for (int q = 0; q < 8; ++q) a[q] = 0.f;
    for (int c = beg; c < end; c += 64) {
      unsigned eidx = idx[min(c + lane, end - 1)];
      int nit = min(end - c, 64);
      for (int k = 0; k < nit; k += 32) {
        int k0 = k + r8, k1 = k0 + 8, k2 = k0 + 16, k3 = k0 + 24;
        int v0 = (int)(__shfl(eidx, min(k0, nit - 1)) >> 18);
        int v1 = (int)(__shfl(eidx, min(k1, nit - 1)) >> 18);
        int v2 = (int)(__shfl(eidx, min(k2, nit - 1)) >> 18);
        int v3 = (int)(__shfl(eidx, min(k3, nit - 1)) >> 18);
        uint4 u0 = *(const uint4*)(te + ((size_t)v0 << 6) + s8);
        uint4 u1 = *(const uint4*)(te + ((size_t)v1 << 6) + s8);
        uint4 u2 = *(const uint4*)(te + ((size_t)v2 << 6) + s8);
        uint4 u3 = *(const uint4*)(te + ((size_t)v3 << 6) + s8);
        acc8h(a, u0, (k0 < nit) ? 1.f : 0.f);
        acc8h(a, u1, (k1 < nit) ? 1.f : 0.f);
        acc8h(a, u2, (k2 < nit) ? 1.f : 0.f);
        acc8h(a, u3, (k3 < nit) ? 1.f : 0.f);
      }
    }
#pragma unroll
    for (int q = 0; q < 8; ++q) {
      a[q] += __shfl_xor(a[q], 8);
      a[q] += __shfl_xor(a[q], 16);
      a[q] += __shfl_xor(a[q], 32);
    }
    int deg = end - beg;
    float inv = (deg > 0) ? 1.f / (float)deg : 0.f;
    if (lane < 8) {
      const float* tp = trb + ((size_t)x[node] << 6) + s8;
      float4 t0 = *(const float4*)tp;
      float4 t1 = *(const float4*)(tp + 4);
      float4 h0, h1;
      h0.x = fmaxf(fmaf(a[0], inv, t0.x), 0.f);
      h0.y = fmaxf(fmaf(a[1], inv, t0.y), 0.f);
      h0.z = fmaxf(fmaf(a[2], inv, t0.z), 0.f);
      h0.w = fmaxf(fmaf(a[3], inv, t0.w), 0.f);
      h1.x = fmaxf(fmaf(a[4], inv, t1.x), 0.f);
      h1.y = fmaxf(fmaf(a[5], inv, t1.y), 0.f);
      h1.z = fmaxf(fmaf(a[6], inv, t1.z), 0.f);
      h1.w = fmaxf(fmaf(a[7], inv, t1.w), 0.f);
      *(float4*)&sm[wid * NPW + i][s8] = h0;
      *(float4*)&sm[wid * NPW + i][s8 + 4] = h1;
    }
  }

  // ---- phase 2: batched epilogue for NPW nodes (weights amortized) ----
  float b2v = b2[lane];
  float aL[NPW], aR[NPW];
#pragma unroll
  for (int i = 0; i < NPW; ++i) { aL[i] = 0.f; aR[i] = b2v; }
  const float* smw = sm[wid * NPW];
#pragma unroll 8
  for (int f = 0; f < 64; ++f) {
    float wl = w2lT[f * 64 + lane];
    float wr = w2rT[f * 64 + lane];
#pragma unroll
    for (int i = 0; i < NPW; ++i) {
      float h = smw[i * 64 + f];
      aL[i] = fmaf(h, wl, aL[i]);
      aR[i] = fmaf(h, wr, aR[i]);
    }
  }
  for (int i = 0; i < nvalid; ++i) {
    int node = nbase + i;
    g1[((size_t)node << 6) + lane] = __float2half(aL[i]);
    s1[((size_t)node << 6) + lane] = aR[i];
  }
}

// conv2: per 64-edge chunk one coalesced idx load; 8 fp16 rows per gather via
// shfl-broadcast indices. o[n] = relu(mean + s1) @ Wout^T.
__global__ void k_conv2(const unsigned* __restrict__ idx, const int* __restrict__ offs,
                        const __half* __restrict__ g1, const float* __restrict__ s1,
                        const float* __restrict__ wout, float* __restrict__ o,
                        int n_nodes) {
  __shared__ float sm[NPB][64];
  int wid = threadIdx.x >> 6, lane = threadIdx.x & 63;
  int r8 = lane >> 3, s8 = (lane & 7) << 3;
  int node = blockIdx.x * NPB + wid;
  bool active = node < n_nodes;
  if (active) {
    int beg = offs[node], end = offs[node + 1];
    float a[8];
#pragma unroll
    for (int q = 0; q < 8; ++q) a[q] = 0.f;
    for (int c = beg; c < end; c += 64) {
      unsigned eidx = idx[min(c + lane, end - 1)];
      int nit = min(end - c, 64);
      for (int k = 0; k < nit; k += 32) {
        int k0 = k + r8, k1 = k0 + 8, k2 = k0 + 16, k3 = k0 + 24;
        int v0 = (int)(__shfl(eidx, min(k0, nit - 1)) & 0x3FFFFu);
        int v1 = (int)(__shfl(eidx, min(k1, nit - 1)) & 0x3FFFFu);
        int v2 = (int)(__shfl(eidx, min(k2, nit - 1)) & 0x3FFFFu);
        int v3 = (int)(__shfl(eidx, min(k3, nit - 1)) & 0x3FFFFu);
        uint4 u0 = *(const uint4*)(g1 + ((size_t)v0 << 6) + s8);
        uint4 u1 = *(const uint4*)(g1 + ((size_t)v1 << 6) + s8);
        uint4 u2 = *(const uint4*)(g1 + ((size_t)v2 << 6) + s8);
        uint4 u3 = *(const uint4*)(g1 + ((size_t)v3 << 6) + s8);
        acc8h(a, u0, (k0 < nit) ? 1.f : 0.f);
        acc8h(a, u1, (k1 < nit) ? 1.f : 0.f);
        acc8h(a, u2, (k2 < nit) ? 1.f : 0.f);
        acc8h(a, u3, (k3 < nit) ? 1.f : 0.f);
      }
    }
#pragma unroll
    for (int q = 0; q < 8; ++q) {
      a[q] += __shfl_xor(a[q], 8);
      a[q] += __shfl_xor(a[q], 16);
      a[q] += __shfl_xor(a[q], 32);
    }
    int deg = end - beg;
    float inv = (deg > 0) ? 1.f / (float)deg : 0.f;
    if (lane < 8) {
#pragma unroll
      for (int q = 0; q < 8; ++q) sm[wid][s8 + q] = a[q] * inv;
    }
  }
  __syncthreads();
  if (active) {
    float h2 = fmaxf(sm[wid][lane] + s1[((size_t)node << 6) + lane], 0.f);
    float p0 = h2 * wout[lane];
    float p1 = h2 * wout[64 + lane];
    for (int off = 32; off > 0; off >>= 1) {
      p0 += __shfl_down(p0, off);
      p1 += __shfl_down(p1, off);
    }
    if (lane == 0) {
      o[((size_t)node << 1) + 0] = p0;
      o[((size_t)node << 1) + 1] = p1;
    }
  }
}

__global__ void k_goffs(const int* __restrict__ batch, int* __restrict__ goffs,
                        int n_nodes, int n_graphs) {
  int i = blockIdx.x * blockDim.x + threadIdx.x;
  if (i >= n_nodes) return;
  int b = batch[i];
  int bp = (i == 0) ? -1 : batch[i - 1];
  for (int g = bp + 1; g <= b; ++g) goffs[g] = i;
  if (i == n_nodes - 1)
    for (int g = b + 1; g <= n_graphs; ++g) goffs[g] = n_nodes;
}

__global__ void k_pool(const float2* __restrict__ o, const int* __restrict__ goffs,
                       const float* __restrict__ bout, float* __restrict__ out,
                       int n_graphs) {
  int wid = threadIdx.x >> 6, lane = threadIdx.x & 63;
  int g = blockIdx.x * NPB + wid;
  if (g >= n_graphs) return;
  int beg = goffs[g], end = goffs[g + 1];
  float a0 = 0.f, a1 = 0.f;
  for (int n = beg + lane; n < end; n += 64) {
    float2 v = o[n];
    a0 += v.x;
    a1 += v.y;
  }
  for (int off = 32; off > 0; off >>= 1) {
    a0 += __shfl_down(a0, off);
    a1 += __shfl_down(a1, off);
  }
  if (lane == 0) {
    int cnt = end - beg;
    float inv = (cnt > 0) ? 1.f / (float)cnt : 0.f;
    out[g * 2 + 0] = a0 * inv + bout[0];
    out[g * 2 + 1] = a1 * inv + bout[1];
  }
}

extern "C" void kernel_launch(void* const* d_in, const int* in_sizes, int n_in,
                              void* d_out, int out_size, void* d_ws, size_t ws_size,
                              hipStream_t stream) {
  const int* x = (const int*)d_in[0];
  const int* ei = (const int*)d_in[1];
  const int* batch = (const int*)d_in[2];
  const float* emb = (const float*)d_in[3];
  const float* W1l = (const float*)d_in[4];
  const float* b1 = (const float*)d_in[5];
  const float* W1r = (const float*)d_in[6];
  const float* W2l = (const float*)d_in[7];
  const float* b2 = (const float*)d_in[8];
  const float* W2r = (const float*)d_in[9];
  const float* Wout = (const float*)d_in[10];
  const float* bout = (const float*)d_in[11];
  float* out = (float*)d_out;

  int n_nodes = in_sizes[0];
  int n_edges = in_sizes[1] / 2;
  int vocab = in_sizes[3] / 64;
  int n_graphs = out_size / 2;
  const int* src = ei;
  const int* dst = ei + n_edges;

  char* p = (char*)d_ws;
  auto alloc = [&](size_t bytes) -> void* {
    void* r = (void*)p;
    p += (bytes + 255) & ~(size_t)255;
    return r;
  };
  __half* te = (__half*)alloc((size_t)vocab * 64 * 2);
  float* trb = (float*)alloc((size_t)vocab * 64 * 4);
  float* wt = (float*)alloc(4 * 4096 * 4);
  int* offs = (int*)alloc((size_t)(n_nodes + 1) * 4);
  int* goffs = (int*)alloc((size_t)(n_graphs + 1) * 4);
  int* btot = (int*)alloc(NBUCK * 4);
  int* bbase = (int*)alloc((NBUCK + 1) * 4);
  int* gcur = (int*)alloc(NBUCK * 4);
  unsigned* idx = (unsigned*)alloc((size_t)n_edges * 4);   // packed (x[src]<<18)|src
  unsigned* pairs = (unsigned*)alloc((size_t)n_edges * 4); // reused as g1 after k_bucket
  float* s1 = (float*)alloc((size_t)n_nodes * 64 * 4);
  float* o = (float*)alloc((size_t)n_nodes * 2 * 4);
  __half* g1 = (__half*)pairs;  // pairs dead before k_conv1 writes g1

  hipMemsetAsync(btot, 0, NBUCK * 4, stream);

  k_transpose4<<<4, 256, 0, stream>>>(W1l, W1r, W2l, W2r, wt);
  k_prep<<<(vocab + NPB - 1) / NPB, 64 * NPB, 0, stream>>>(emb, wt, wt + 4096, b1, te, trb, vocab);

  k_bhist<<<1024, 256, 0, stream>>>(dst, btot, n_edges, n_nodes);
  k_bscan<<<1, NBUCK, 0, stream>>>(btot, bbase, gcur, n_edges);
  int part_blocks = 512;
  int chunk = (n_edges + part_blocks - 1) / part_blocks;
  k_part<<<part_blocks, 256, 0, stream>>>(src, dst, gcur, pairs, n_edges, n_nodes, chunk);
  k_bucket<<<NBUCK, 256, 0, stream>>>(pairs, bbase, x, offs, idx, n_nodes, n_edges);

  k_goffs<<<(n_nodes + 255) / 256, 256, 0, stream>>>(batch, goffs, n_nodes, n_graphs);

  int npb1 = NPB * NPW;  // nodes per block in conv1
  k_conv1<<<(n_nodes + npb1 - 1) / npb1, 64 * NPB, 0, stream>>>(idx, offs, te, trb, x, wt + 8192, wt + 12288, b2, g1, s1, n_nodes);
  k_conv2<<<(n_nodes + NPB - 1) / NPB, 64 * NPB, 0, stream>>>(idx, offs, g1, s1, Wout, o, n_nodes);
  k_pool<<<(n_graphs + NPB - 1) / NPB, 64 * NPB, 0, stream>>>((const float2*)o, goffs, bout, out, n_graphs);
}

// Round 8
// 437.689 us; speedup vs baseline: 3.6063x; 1.0860x over previous
//
#include <hip/hip_runtime.h>
#include <hip/hip_fp16.h>
#include <stdint.h>

// GNN: 2x SAGEConv(mean)+ReLU + mean-pool + linear, algebraically refactored:
//  te = emb@W1l^T (fp16, L2-resident gather table), trb = emb@W1r^T + b1 (fp32)
//  conv1: h1 = relu(mean(te[x[src]]) + trb[x[n]]); g1 = h1@W2l^T (fp16); s1 = h1@W2r^T + b2
//  conv2: h2 = relu(mean(g1[src]) + s1[n]); o[n] = h2@Wout^T
//  pool:  out[g] = mean(o) + bout
// idx[pos] = (x[src]<<18) | src  (vocab<2^14, n_nodes<2^18).
// CSR build: k_part scatters into fixed-stride over-provisioned bucket regions
// (CAP; dst uniform -> 26-sigma headroom), counts = gcur[b]-b*CAP -> no k_bhist.
// Convs: 64-thr blocks; unmasked fast path for full 32-edge groups.

#define NPW 4       // nodes per wave in conv1 (epilogue amortization)
#define NPB 4       // waves per block (pool)
#define NBUCK 256   // dst buckets
#define TILE 4096   // edges per partition tile
#define EPT 16      // TILE / 256
#define MAXN 1024   // >= ceil(n_nodes / NBUCK)

__device__ __forceinline__ int bucket_of(int dstv, int n_nodes) {
  return (int)(((unsigned)dstv * 256u) / (unsigned)n_nodes);  // NBUCK=256
}

__device__ __forceinline__ void acc8h(float* a, uint4 u, float m) {
  const __half2* hp = (const __half2*)&u;
#pragma unroll
  for (int q = 0; q < 4; ++q) {
    float2 f = __half22float2(hp[q]);
    a[2 * q]     = fmaf(m, f.x, a[2 * q]);
    a[2 * q + 1] = fmaf(m, f.y, a[2 * q + 1]);
  }
}

__device__ __forceinline__ void acc8h_nm(float* a, uint4 u) {
  const __half2* hp = (const __half2*)&u;
#pragma unroll
  for (int q = 0; q < 4; ++q) {
    float2 f = __half22float2(hp[q]);
    a[2 * q]     += f.x;
    a[2 * q + 1] += f.y;
  }
}

__global__ void k_init(int* __restrict__ gcur, int cap) {
  gcur[threadIdx.x] = threadIdx.x * cap;
}

// LDS-tile multisplit: scatter packed (dloc<<18 | src) into per-bucket regions
__global__ void k_part(const int* __restrict__ src, const int* __restrict__ dst,
                       int* __restrict__ gcur, unsigned* __restrict__ pairs,
                       int n_edges, int n_nodes, int chunk) {
  __shared__ int hist[NBUCK];
  __shared__ int base[NBUCK];
  int t = threadIdx.x;
  int beg = blockIdx.x * chunk;
  int end = min(beg + chunk, n_edges);
  for (int tbeg = beg; tbeg < end; tbeg += TILE) {
    int cnt = min(TILE, end - tbeg);
    hist[t] = 0;
    __syncthreads();
    unsigned pk[EPT];
    int r[EPT], bk[EPT];
    bool v[EPT];
#pragma unroll
    for (int k = 0; k < EPT; ++k) {
      int li = k * 256 + t;
      v[k] = li < cnt;
      if (v[k]) {
        int i = tbeg + li;
        int s = src[i];
        int d = dst[i];
        bk[k] = bucket_of(d, n_nodes);
        unsigned nb0 = ((unsigned)bk[k] * (unsigned)n_nodes + 255u) >> 8;
        pk[k] = (((unsigned)d - nb0) << 18) | (unsigned)s;
        r[k] = atomicAdd(&hist[bk[k]], 1);
      }
    }
    __syncthreads();
    base[t] = (hist[t] > 0) ? atomicAdd(&gcur[t], hist[t]) : 0;
    __syncthreads();
#pragma unroll
    for (int k = 0; k < EPT; ++k)
      if (v[k]) pairs[base[bk[k]] + r[k]] = pk[k];
    __syncthreads();
  }
}

// scan of bucket counts (gcur[b]-b*cap) -> dense output bases
__global__ void k_bscan2(const int* __restrict__ gcur, int* __restrict__ bbase,
                         int cap, int n_edges) {
  __shared__ int s[NBUCK];
  int t = threadIdx.x;
  s[t] = gcur[t] - t * cap;
  __syncthreads();
  for (int off = 1; off < NBUCK; off <<= 1) {
    int add = (t >= off) ? s[t - off] : 0;
    __syncthreads();
    s[t] += add;
    __syncthreads();
  }
  bbase[t] = (t == 0) ? 0 : s[t - 1];
  if (t == NBUCK - 1) bbase[NBUCK] = n_edges;
}

// one block per bucket: LDS node-hist -> scan -> offs; scatter packed (x[src]<<18|src)
__global__ void k_bucket(const unsigned* __restrict__ pairs, const int* __restrict__ gcur,
                         const int* __restrict__ bbase, const int* __restrict__ x,
                         int* __restrict__ offs, unsigned* __restrict__ idx,
                         int n_nodes, int n_edges, int cap) {
  __shared__ int lcnt[MAXN];
  __shared__ int lcur[MAXN];
  __shared__ int stmp[256];
  int b = blockIdx.x, t = threadIdx.x;
  int nb0 = (int)((((unsigned)b * (unsigned)n_nodes) + 255u) >> 8);
  int nb1 = (int)((((unsigned)(b + 1) * (unsigned)n_nodes) + 255u) >> 8);
  if (nb1 > n_nodes) nb1 = n_nodes;
  int nn = nb1 - nb0;
  int rbeg = b * cap;
  int rend = gcur[b];
  int obase = bbase[b];
  for (int i = t; i < nn; i += 256) lcnt[i] = 0;
  __syncthreads();
  for (int i = rbeg + t; i < rend; i += 256)
    atomicAdd(&lcnt[pairs[i] >> 18], 1);
  __syncthreads();
  int i0 = t * 4;
  int v0 = (i0 + 0 < nn) ? lcnt[i0 + 0] : 0;
  int v1 = (i0 + 1 < nn) ? lcnt[i0 + 1] : 0;
  int v2 = (i0 + 2 < nn) ? lcnt[i0 + 2] : 0;
  int v3 = (i0 + 3 < nn) ? lcnt[i0 + 3] : 0;
  stmp[t] = v0 + v1 + v2 + v3;
  __syncthreads();
  for (int off = 1; off < 256; off <<= 1) {
    int add = (t >= off) ? stmp[t - off] : 0;
    __syncthreads();
    stmp[t] += add;
    __syncthreads();
  }
  int run = obase + ((t == 0) ? 0 : stmp[t - 1]);
  if (i0 + 0 < nn) { lcur[i0 + 0] = run; offs[nb0 + i0 + 0] = run; run += v0; }
  if (i0 + 1 < nn) { lcur[i0 + 1] = run; offs[nb0 + i0 + 1] = run; run += v1; }
  if (i0 + 2 < nn) { lcur[i0 + 2] = run; offs[nb0 + i0 + 2] = run; run += v2; }
  if (i0 + 3 < nn) { lcur[i0 + 3] = run; offs[nb0 + i0 + 3] = run; run += v3; }
  if (b == NBUCK - 1 && t == 0) offs[n_nodes] = n_edges;
  __syncthreads();
  for (int i = rbeg + t; i < rend; i += 256) {
    unsigned e = pairs[i];
    int s = (int)(e & 0x3FFFFu);
    int pos = atomicAdd(&lcur[e >> 18], 1);
    idx[pos] = ((unsigned)x[s] << 18) | (unsigned)s;
  }
}

__global__ void k_transpose4(const float* __restrict__ a0, const float* __restrict__ a1,
                             const float* __restrict__ a2, const float* __restrict__ a3,
                             float* __restrict__ wt) {
  const float* s = (blockIdx.x == 0) ? a0 : (blockIdx.x == 1) ? a1 : (blockIdx.x == 2) ? a2 : a3;
  float* d = wt + blockIdx.x * 4096;
  for (int i = threadIdx.x; i < 4096; i += blockDim.x) {
    int r = i >> 6, c = i & 63;
    d[c * 64 + r] = s[i];
  }
}

// te = emb@W1l^T (fp16) ; trb = emb@W1r^T + b1 (fp32)   (wave per vocab row)
__global__ void k_prep(const float* __restrict__ emb, const float* __restrict__ w1lT,
                       const float* __restrict__ w1rT, const float* __restrict__ b1,
                       __half* __restrict__ te, float* __restrict__ trb, int vocab) {
  __shared__ float se[NPB][64];
  int wid = threadIdx.x >> 6, lane = threadIdx.x & 63;
  int v = blockIdx.x * NPB + wid;
  if (v >= vocab) return;
  se[wid][lane] = emb[(size_t)v * 64 + lane];
  __syncwarp();
  float aL = 0.f, aR = b1[lane];
#pragma unroll 8
  for (int f = 0; f < 64; ++f) {
    float ev = se[wid][f];
    aL = fmaf(ev, w1lT[f * 64 + lane], aL);
    aR = fmaf(ev, w1rT[f * 64 + lane], aR);
  }
  te[(size_t)v * 64 + lane] = __float2half(aL);
  trb[(size_t)v * 64 + lane] = aR;
}

// conv1: 1 wave/block, NPW nodes sequential; unmasked full 32-edge groups;
// batched epilogue (per f: 2 weight loads + 4 LDS broadcasts + 8 fma).
__global__ __launch_bounds__(64) void
k_conv1(const unsigned* __restrict__ idx, const int* __restrict__ offs,
        const __half* __restrict__ te, const float* __restrict__ trb,
        const int* __restrict__ x, const float* __restrict__ w2lT,
        const float* __restrict__ w2rT, const float* __restrict__ b2,
        __half* __restrict__ g1, float* __restrict__ s1, int n_nodes) {
  __shared__ float sm[NPW][64];
  int lane = threadIdx.x;
  int r8 = lane >> 3, s8 = (lane & 7) << 3;
  int nbase = blockIdx.x * NPW;
  if (nbase >= n_nodes) return;
  int nvalid = min(NPW, n_nodes - nbase);

  for (int i = 0; i < nvalid; ++i) {
    int node = nbase + i;
    int beg = offs[node], end = offs[node + 1];
    float a[8];
#pragma unroll
    for (int q = 0; q < 8; ++q) a[q] = 0.f;
    for (int c = beg; c < end; c += 64) {
      int nit = min(end - c, 64);
      unsigned eidx = idx[c + min(lane, nit - 1)];
      int nfull = nit & ~31;
      for (int k = 0; k < nfull; k += 32) {
        int k0 = k + r8;
        int v0 = (int)(__shfl(eidx, k0) >> 18);
        int v1 = (int)(__shfl(eidx, k0 + 8) >> 18);
        int v2 = (int)(__shfl(eidx, k0 + 16) >> 18);
        int v3 = (int)(__shfl(eidx, k0 + 24) >> 18);
        uint4 u0 = *(const uint4*)(te + ((size_t)v0 << 6) + s8);
        uint4 u1 = *(const uint4*)(te + ((size_t)v1 << 6) + s8);
        uint4 u2 = *(const uint4*)(te + ((size_t)v2 << 6) + s8);
        uint4 u3 = *(const uint4*)(te + ((size_t)v3 << 6) + s8);
        acc8h_nm(a, u0);
        acc8h_nm(a, u1);
        acc8h_nm(a, u2);
        acc8h_nm(a, u3);
      }
      if (nit & 31) {
        int k0 = nfull + r8, k1 = k0 + 8, k2 = k0 + 16, k3 = k0 + 24;
        int v0 = (int)(__shfl(eidx, min(k0, nit - 1)) >> 18);
        int v1 = (int)(__shfl(eidx, min(k1, nit - 1)) >> 18);
        int v2 = (int)(__shfl(eidx, min(k2, nit - 1)) >> 18);
        int v3 = (int)(__shfl(eidx, min(k3, nit - 1)) >> 18);
        uint4 u0 = *(const uint4*)(te + ((size_t)v0 << 6) + s8);
        uint4 u1 = *(const uint4*)(te + ((size_t)v1 << 6) + s8);
        uint4 u2 = *(const uint4*)(te + ((size_t)v2 << 6) + s8);
        uint4 u3 = *(const uint4*)(te + ((size_t)v3 << 6) + s8);
        acc8h(a, u0, (k0 < nit) ? 1.f : 0.f);
        acc8h(a, u1, (k1 < nit) ? 1.f : 0.f);
        acc8h(a, u2, (k2 < nit) ? 1.f : 0.f);
        acc8h(a, u3, (k3 < nit) ? 1.f : 0.f);
      }
    }
#pragma unroll
    for (int q = 0; q < 8; ++q) {
      a[q] += __shfl_xor(a[q], 8);
      a[q] += __shfl_xor(a[q], 16);
      a[q] += __shfl_xor(a[q], 32);
    }
    int deg = end - beg;
    float inv = (deg > 0) ? 1.f / (float)deg : 0.f;
    if (lane < 8) {
      const float* tp = trb + ((size_t)x[node] << 6) + s8;
      float4 t0 = *(const float4*)tp;
      float4 t1 = *(const float4*)(tp + 4);
      float4 h0, h1;
      h0.x = fmaxf(fmaf(a[0], inv, t0.x), 0.f);
      h0.y = fmaxf(fmaf(a[1], inv, t0.y), 0.f);
      h0.z = fmaxf(fmaf(a[2], inv, t0.z), 0.f);
      h0.w = fmaxf(fmaf(a[3], inv, t0.w), 0.f);
      h1.x = fmaxf(fmaf(a[4], inv, t1.x), 0.f);
      h1.y = fmaxf(fmaf(a[5], inv, t1.y), 0.f);
      h1.z = fmaxf(fmaf(a[6], inv, t1.z), 0.f);
      h1.w = fmaxf(fmaf(a[7], inv, t1.w), 0.f);
      *(float4*)&sm[i][s8] = h0;
      *(float4*)&sm[i][s8 + 4] = h1;
    }
  }
  __syncthreads();

  float b2v = b2[lane];
  float aL[NPW], aR[NPW];
#pragma unroll
  for (int i = 0; i < NPW; ++i) { aL[i] = 0.f; aR[i] = b2v; }
  const float* smw = &sm[0][0];
#pragma unroll 8
  for (int f = 0; f < 64; ++f) {
    float wl = w2lT[f * 64 + lane];
    float wr = w2rT[f * 64 + lane];
#pragma unroll
    for (int i = 0; i < NPW; ++i) {
      float h = smw[i * 64 + f];
      aL[i] = fmaf(h, wl, aL[i]);
      aR[i] = fmaf(h, wr, aR[i]);
    }
  }
  for (int i = 0; i < nvalid; ++i) {
    int node = nbase + i;
    g1[((size_t)node << 6) + lane] = __float2half(aL[i]);
    s1[((size_t)node << 6) + lane] = aR[i];
  }
}

// conv2: 1 wave/block, 1 node; unmasked full groups; o[n]=relu(mean+s1)@Wout^T
__global__ __launch_bounds__(64) void
k_conv2(const unsigned* __restrict__ idx, const int* __restrict__ offs,
        const __half* __restrict__ g1, const float* __restrict__ s1,
        const float* __restrict__ wout, float* __restrict__ o, int n_nodes) {
  __shared__ float sm[64];
  int lane = threadIdx.x;
  int r8 = lane >> 3, s8 = (lane & 7) << 3;
  int node = blockIdx.x;
  if (node >= n_nodes) return;
  int beg = offs[node], end = offs[node + 1];
  float a[8];
#pragma unroll
  for (int q = 0; q < 8; ++q) a[q] = 0.f;
  for (int c = beg; c < end; c += 64) {
    int nit = min(end - c, 64);
    unsigned eidx = idx[c + min(lane, nit - 1)];
    int nfull = nit & ~31;
    for (int k = 0; k < nfull; k += 32) {
      int k0 = k + r8;
      int v0 = (int)(__shfl(eidx, k0) & 0x3FFFFu);
      int v1 = (int)(__shfl(eidx, k0 + 8) & 0x3FFFFu);
      int v2 = (int)(__shfl(eidx, k0 + 16) & 0x3FFFFu);
      int v3 = (int)(__shfl(eidx, k0 + 24) & 0x3FFFFu);
      uint4 u0 = *(const uint4*)(g1 + ((size_t)v0 << 6) + s8);
      uint4 u1 = *(const uint4*)(g1 + ((size_t)v1 << 6) + s8);
      uint4 u2 = *(const uint4*)(g1 + ((size_t)v2 << 6) + s8);
      uint4 u3 = *(const uint4*)(g1 + ((size_t)v3 << 6) + s8);
      acc8h_nm(a, u0);
      acc8h_nm(a, u1);
      acc8h_nm(a, u2);
      acc8h_nm(a, u3);
    }
    if (nit & 31) {
      int k0 = nfull + r8, k1 = k0 + 8, k2 = k0 + 16, k3 = k0 + 24;
      int v0 = (int)(__shfl(eidx, min(k0, nit - 1)) & 0x3FFFFu);
      int v1 = (int)(__shfl(eidx, min(k1, nit - 1)) & 0x3FFFFu);
      int v2 = (int)(__shfl(eidx, min(k2, nit - 1)) & 0x3FFFFu);
      int v3 = (int)(__shfl(eidx, min(k3, nit - 1)) & 0x3FFFFu);
      uint4 u0 = *(const uint4*)(g1 + ((size_t)v0 << 6) + s8);
      uint4 u1 = *(const uint4*)(g1 + ((size_t)v1 << 6) + s8);
      uint4 u2 = *(const uint4*)(g1 + ((size_t)v2 << 6) + s8);
      uint4 u3 = *(const uint4*)(g1 + ((size_t)v3 << 6) + s8);
      acc8h(a, u0, (k0 < nit) ? 1.f : 0.f);
      acc8h(a, u1, (k1 < nit) ? 1.f : 0.f);
      acc8h(a, u2, (k2 < nit) ? 1.f : 0.f);
      acc8h(a, u3, (k3 < nit) ? 1.f : 0.f);
    }
  }
#pragma unroll
  for (int q = 0; q < 8; ++q) {
    a[q] += __shfl_xor(a[q], 8);
    a[q] += __shfl_xor(a[q], 16);
    a[q] += __shfl_xor(a[q], 32);
  }
  int deg = end - beg;
  float inv = (deg > 0) ? 1.f / (float)deg : 0.f;
  if (lane < 8) {
#pragma unroll
    for (int q = 0; q < 8; ++q) sm[s8 + q] = a[q] * inv;
  }
  __syncthreads();
  float h2 = fmaxf(sm[lane] + s1[((size_t)node << 6) + lane], 0.f);
  float p0 = h2 * wout[lane];
  float p1 = h2 * wout[64 + lane];
  for (int off = 32; off > 0; off >>= 1) {
    p0 += __shfl_down(p0, off);
    p1 += __shfl_down(p1, off);
  }
  if (lane == 0) {
    o[((size_t)node << 1) + 0] = p0;
    o[((size_t)node << 1) + 1] = p1;
  }
}

__global__ void k_goffs(const int* __restrict__ batch, int* __restrict__ goffs,
                        int n_nodes, int n_graphs) {
  int i = blockIdx.x * blockDim.x + threadIdx.x;
  if (i >= n_nodes) return;
  int b = batch[i];
  int bp = (i == 0) ? -1 : batch[i - 1];
  for (int g = bp + 1; g <= b; ++g) goffs[g] = i;
  if (i == n_nodes - 1)
    for (int g = b + 1; g <= n_graphs; ++g) goffs[g] = n_nodes;
}

__global__ void k_pool(const float2* __restrict__ o, const int* __restrict__ goffs,
                       const float* __restrict__ bout, float* __restrict__ out,
                       int n_graphs) {
  int wid = threadIdx.x >> 6, lane = threadIdx.x & 63;
  int g = blockIdx.x * NPB + wid;
  if (g >= n_graphs) return;
  int beg = goffs[g], end = goffs[g + 1];
  float a0 = 0.f, a1 = 0.f;
  for (int n = beg + lane; n < end; n += 64) {
    float2 v = o[n];
    a0 += v.x;
    a1 += v.y;
  }
  for (int off = 32; off > 0; off >>= 1) {
    a0 += __shfl_down(a0, off);
    a1 += __shfl_down(a1, off);
  }
  if (lane == 0) {
    int cnt = end - beg;
    float inv = (cnt > 0) ? 1.f / (float)cnt : 0.f;
    out[g * 2 + 0] = a0 * inv + bout[0];
    out[g * 2 + 1] = a1 * inv + bout[1];
  }
}

extern "C" void kernel_launch(void* const* d_in, const int* in_sizes, int n_in,
                              void* d_out, int out_size, void* d_ws, size_t ws_size,
                              hipStream_t stream) {
  const int* x = (const int*)d_in[0];
  const int* ei = (const int*)d_in[1];
  const int* batch = (const int*)d_in[2];
  const float* emb = (const float*)d_in[3];
  const float* W1l = (const float*)d_in[4];
  const float* b1 = (const float*)d_in[5];
  const float* W1r = (const float*)d_in[6];
  const float* W2l = (const float*)d_in[7];
  const float* b2 = (const float*)d_in[8];
  const float* W2r = (const float*)d_in[9];
  const float* Wout = (const float*)d_in[10];
  const float* bout = (const float*)d_in[11];
  float* out = (float*)d_out;

  int n_nodes = in_sizes[0];
  int n_edges = in_sizes[1] / 2;
  int vocab = in_sizes[3] / 64;
  int n_graphs = out_size / 2;
  const int* src = ei;
  const int* dst = ei + n_edges;

  // over-provisioned bucket region stride (dst uniform -> huge sigma margin)
  int cap = n_edges / NBUCK + n_edges / (NBUCK * 8) + 1024;

  char* p = (char*)d_ws;
  auto alloc = [&](size_t bytes) -> void* {
    void* r = (void*)p;
    p += (bytes + 255) & ~(size_t)255;
    return r;
  };
  __half* te = (__half*)alloc((size_t)vocab * 64 * 2);
  float* trb = (float*)alloc((size_t)vocab * 64 * 4);
  float* wt = (float*)alloc(4 * 4096 * 4);
  int* offs = (int*)alloc((size_t)(n_nodes + 1) * 4);
  int* goffs = (int*)alloc((size_t)(n_graphs + 1) * 4);
  int* bbase = (int*)alloc((NBUCK + 1) * 4);
  int* gcur = (int*)alloc(NBUCK * 4);
  unsigned* idx = (unsigned*)alloc((size_t)n_edges * 4);      // packed (x[src]<<18)|src
  size_t pairs_bytes = (size_t)NBUCK * cap * 4;
  size_t g1_bytes = (size_t)n_nodes * 64 * 2;
  unsigned* pairs = (unsigned*)alloc(pairs_bytes > g1_bytes ? pairs_bytes : g1_bytes);
  float* s1 = (float*)alloc((size_t)n_nodes * 64 * 4);
  float* o = (float*)alloc((size_t)n_nodes * 2 * 4);
  __half* g1 = (__half*)pairs;  // pairs dead before k_conv1 writes g1

  k_init<<<1, NBUCK, 0, stream>>>(gcur, cap);
  k_transpose4<<<4, 256, 0, stream>>>(W1l, W1r, W2l, W2r, wt);
  k_prep<<<(vocab + NPB - 1) / NPB, 64 * NPB, 0, stream>>>(emb, wt, wt + 4096, b1, te, trb, vocab);

  int part_blocks = 512;
  int chunk = (n_edges + part_blocks - 1) / part_blocks;
  k_part<<<part_blocks, 256, 0, stream>>>(src, dst, gcur, pairs, n_edges, n_nodes, chunk);
  k_bscan2<<<1, NBUCK, 0, stream>>>(gcur, bbase, cap, n_edges);
  k_bucket<<<NBUCK, 256, 0, stream>>>(pairs, gcur, bbase, x, offs, idx, n_nodes, n_edges, cap);

  k_goffs<<<(n_nodes + 255) / 256, 256, 0, stream>>>(batch, goffs, n_nodes, n_graphs);

  k_conv1<<<(n_nodes + NPW - 1) / NPW, 64, 0, stream>>>(idx, offs, te, trb, x, wt + 8192, wt + 12288, b2, g1, s1, n_nodes);
  k_conv2<<<n_nodes, 64, 0, stream>>>(idx, offs, g1, s1, Wout, o, n_nodes);
  k_pool<<<(n_graphs + NPB - 1) / NPB, 64 * NPB, 0, stream>>>((const float2*)o, goffs, bout, out, n_graphs);
}